// Round 1
// baseline (480.289 us; speedup 1.0000x reference)
//
#include <hip/hip_runtime.h>
#include <hip/hip_bf16.h>
#include <cstdint>
#include <cstddef>

// ---------------- types & helpers ----------------
typedef __attribute__((ext_vector_type(4))) float f32x4;
typedef __attribute__((ext_vector_type(8))) short s16x8;       // 8 bf16 (4 VGPRs) MFMA frag
typedef __attribute__((ext_vector_type(4))) unsigned int u32x4;
typedef __attribute__((ext_vector_type(4))) unsigned short u16x4;

__device__ __forceinline__ unsigned short f2bf(float f) {
  union { float f; unsigned int u; } v; v.f = f;
  return (unsigned short)((v.u + 0x7fffu + ((v.u >> 16) & 1u)) >> 16);  // RNE
}

__device__ __forceinline__ void gll16(const void* g, void* l) {
  // async global->LDS, 16B per lane. LDS dest must be wave-uniform base + lane*16.
  __builtin_amdgcn_global_load_lds(
      (const __attribute__((address_space(1))) void*)g,
      (__attribute__((address_space(3))) void*)l, 16, 0, 0);
}

// ---------------- mask dtype detector ----------------
// flag=1: mask is byte-typed (bool). flag=0: mask is int32 0/1.
// Bernoulli(0.1) over 64KB: byte format surely has nonzero bytes at offset%4!=0.
__global__ void mask_detect(const unsigned char* __restrict__ m, int* __restrict__ flag) {
  __shared__ int f;
  if (threadIdx.x == 0) f = 0;
  __syncthreads();
  unsigned int found = 0;
  for (int i = threadIdx.x * 16; i < 65536; i += 256 * 16) {
    u32x4 v = *(const u32x4*)(m + i);
    found |= (v.x & 0xFFFFFF00u) | (v.y & 0xFFFFFF00u) |
             (v.z & 0xFFFFFF00u) | (v.w & 0xFFFFFF00u);
  }
  if (found) atomicOr(&f, 1);
  __syncthreads();
  if (threadIdx.x == 0) *flag = f;
}

// ---------------- LayerNorm (fp32 in -> bf16 out), one row per block ----------------
__global__ __launch_bounds__(256)
void ln_bf16(const float* __restrict__ x, const float* __restrict__ g,
             const float* __restrict__ bta, unsigned short* __restrict__ out) {
  const int row = blockIdx.x;
  const int t = threadIdx.x;
  const float* xr = x + (size_t)row * 1024;
  f32x4 v = *(const f32x4*)(xr + t * 4);
  float s  = v.x + v.y + v.z + v.w;
  float sq = v.x * v.x + v.y * v.y + v.z * v.z + v.w * v.w;
#pragma unroll
  for (int d = 1; d < 64; d <<= 1) { s += __shfl_xor(s, d, 64); sq += __shfl_xor(sq, d, 64); }
  __shared__ float ss[4], ssq[4];
  const int w = t >> 6;
  if ((t & 63) == 0) { ss[w] = s; ssq[w] = sq; }
  __syncthreads();
  s  = ss[0] + ss[1] + ss[2] + ss[3];
  sq = ssq[0] + ssq[1] + ssq[2] + ssq[3];
  const float mu  = s * (1.0f / 1024.0f);
  const float var = sq * (1.0f / 1024.0f) - mu * mu;
  const float rs  = rsqrtf(var + 1e-5f);
  f32x4 gv = *(const f32x4*)(g + t * 4);
  f32x4 bv = *(const f32x4*)(bta + t * 4);
  u16x4 o;
  o.x = f2bf((v.x - mu) * rs * gv.x + bv.x);
  o.y = f2bf((v.y - mu) * rs * gv.y + bv.y);
  o.z = f2bf((v.z - mu) * rs * gv.z + bv.z);
  o.w = f2bf((v.w - mu) * rs * gv.w + bv.w);
  *(u16x4*)(out + (size_t)row * 1024 + t * 4) = o;
}

// ---------------- fp32 -> bf16 convert (weights) ----------------
__global__ __launch_bounds__(256)
void f32_to_bf16(const float* __restrict__ in, unsigned short* __restrict__ out, int n) {
  for (int i = (blockIdx.x * 256 + threadIdx.x) * 4; i < n; i += gridDim.x * 256 * 4) {
    f32x4 v = *(const f32x4*)(in + i);
    u16x4 o = { f2bf(v.x), f2bf(v.y), f2bf(v.z), f2bf(v.w) };
    *(u16x4*)(out + i) = o;
  }
}

// ---------------- BT-GEMM: C[M,N] = A[M,K] @ B[N,K]^T + bias, epilogues ----------------
// EPI 0: bf16 store. EPI 1: exact GELU -> bf16. EPI 2: + resid -> fp32.
// 128x128 tile, BK=64, 256 threads (2x2 waves of 64x64), 16x16x32 bf16 MFMA.
template<int EPI>
__global__ __launch_bounds__(256)
void gemm_bt(const unsigned short* __restrict__ A, const unsigned short* __restrict__ Bw,
             const float* __restrict__ bias, const float* __restrict__ resid,
             void* __restrict__ Cout, int M, int N, int K) {
  __shared__ unsigned short As[128 * 64];
  __shared__ unsigned short Bs[128 * 64];
  const int tid = threadIdx.x;
  const int bx = blockIdx.x;          // col tile
  const int by = blockIdx.y;          // row tile
  const int w = tid >> 6, l = tid & 63;
  const int wr = w >> 1, wc = w & 1;
  const int lr = l & 15, lk = l >> 4;

  f32x4 acc[4][4] = {};
  const int row0A = by * 128, row0B = bx * 128;

  for (int kt = 0; kt < K; kt += 64) {
#pragma unroll
    for (int it = 0; it < 4; ++it) {
      const int c = it * 256 + tid;
      const int r = c >> 3, c8 = (c & 7) * 8;
      gll16(A  + (size_t)(row0A + r) * K + kt + c8, As + c * 8);
      gll16(Bw + (size_t)(row0B + r) * K + kt + c8, Bs + c * 8);
    }
    asm volatile("s_waitcnt vmcnt(0)" ::: "memory");
    __syncthreads();
#pragma unroll
    for (int ks = 0; ks < 2; ++ks) {
      s16x8 af[4], bfr[4];
#pragma unroll
      for (int m = 0; m < 4; ++m)
        af[m] = *(const s16x8*)&As[(wr * 64 + m * 16 + lr) * 64 + ks * 32 + lk * 8];
#pragma unroll
      for (int n = 0; n < 4; ++n)
        bfr[n] = *(const s16x8*)&Bs[(wc * 64 + n * 16 + lr) * 64 + ks * 32 + lk * 8];
#pragma unroll
      for (int m = 0; m < 4; ++m)
#pragma unroll
        for (int n = 0; n < 4; ++n)
          acc[m][n] = __builtin_amdgcn_mfma_f32_16x16x32_bf16(af[m], bfr[n], acc[m][n], 0, 0, 0);
    }
    __syncthreads();
  }
#pragma unroll
  for (int m = 0; m < 4; ++m) {
#pragma unroll
    for (int n = 0; n < 4; ++n) {
      const int col = bx * 128 + wc * 64 + n * 16 + lr;
      const float bval = bias[col];
#pragma unroll
      for (int r2 = 0; r2 < 4; ++r2) {
        const int row = by * 128 + wr * 64 + m * 16 + lk * 4 + r2;
        float vv = acc[m][n][r2] + bval;
        const size_t idx = (size_t)row * N + col;
        if (EPI == 0) {
          ((unsigned short*)Cout)[idx] = f2bf(vv);
        } else if (EPI == 1) {
          float ge = 0.5f * vv * (1.0f + erff(vv * 0.70710678118f));
          ((unsigned short*)Cout)[idx] = f2bf(ge);
        } else {
          ((float*)Cout)[idx] = vv + resid[idx];
        }
      }
    }
  }
}

// ---------------- flash attention with softmax1 (implicit zero logit) ----------------
// qkv: [4096, 3072] bf16 rows = b*1024+n, cols = {q|k|v}*1024 + h*64 + d
// grid: (b*16+h, qtile). 256 threads = 4 waves, each wave owns 16 Q rows.
__global__ __launch_bounds__(256)
void attn_kernel(const unsigned short* __restrict__ qkv, const void* __restrict__ maskp,
                 const int* __restrict__ flag, unsigned short* __restrict__ o_ws) {
  __shared__ unsigned short Qs[64 * 64];
  __shared__ unsigned short Ks[64 * 64];
  __shared__ unsigned short Vts[64 * 64];      // V transposed: [d][n]
  __shared__ unsigned short Ps[4][16 * 64];    // per-wave P tile
  __shared__ __align__(16) unsigned char Ms[64 * 64];

  const int tid = threadIdx.x;
  const int bh = blockIdx.x, qt = blockIdx.y;
  const int b = bh >> 4, h = bh & 15;
  const int q0 = qt * 64;
  const int w = tid >> 6, l = tid & 63;
  const int lr = l & 15, lk = l >> 4;
  const size_t rowbase = (size_t)b * 1024;
  const int qoff = h * 64, koff = 1024 + h * 64, voff = 2048 + h * 64;

  // Q tile: rows q0..q0+63, 64 cols
#pragma unroll
  for (int it = 0; it < 2; ++it) {
    const int c = it * 256 + tid;
    const int r = c >> 3, c8 = (c & 7) * 8;
    gll16(qkv + (rowbase + q0 + r) * 3072 + qoff + c8, Qs + c * 8);
  }
  const int mask_is_byte = *flag;

  float m_r[4] = {0.f, 0.f, 0.f, 0.f};   // implicit zero logit baseline
  float l_r[4] = {1.f, 1.f, 1.f, 1.f};   // softmax1 denominator seed
  f32x4 acc_o[4] = {};

  for (int nt = 0; nt < 16; ++nt) {
    const int n0 = nt * 64;
    __syncthreads();  // previous-iter consumers done (also drains Q staging at nt=0)
#pragma unroll
    for (int it = 0; it < 2; ++it) {
      const int c = it * 256 + tid;
      const int r = c >> 3, c8 = (c & 7) * 8;
      gll16(qkv + (rowbase + n0 + r) * 3072 + koff + c8, Ks + c * 8);
    }
    {  // V transpose staging: thread -> (n = tid&63, dgroup = tid>>6), 16 d each
      const int n = tid & 63, dg = tid >> 6;
      const u32x4* src = (const u32x4*)(qkv + (rowbase + n0 + n) * 3072 + voff + dg * 16);
      u32x4 v0 = src[0], v1 = src[1];
      const unsigned short* e0 = (const unsigned short*)&v0;
      const unsigned short* e1 = (const unsigned short*)&v1;
#pragma unroll
      for (int j = 0; j < 8; ++j) Vts[(dg * 16 + j) * 64 + n] = e0[j];
#pragma unroll
      for (int j = 0; j < 8; ++j) Vts[(dg * 16 + 8 + j) * 64 + n] = e1[j];
    }
    {  // mask tile -> Ms bytes (both dtypes)
      const int r = tid >> 2, c16 = (tid & 3) * 16;
      const size_t moff = ((size_t)b * 1024 + q0 + r) * 1024 + n0 + c16;
      if (mask_is_byte) {
        *(u32x4*)&Ms[r * 64 + c16] = *(const u32x4*)((const unsigned char*)maskp + moff);
      } else {
        const int* mi = (const int*)maskp + moff;
#pragma unroll
        for (int j = 0; j < 16; ++j) Ms[r * 64 + c16 + j] = (mi[j] != 0) ? 1 : 0;
      }
    }
    asm volatile("s_waitcnt vmcnt(0)" ::: "memory");
    __syncthreads();

    // S = Q @ K^T for this wave's 16 rows x 64 cols
    f32x4 s_acc[4] = {};
#pragma unroll
    for (int ks = 0; ks < 2; ++ks) {
      s16x8 aq = *(const s16x8*)&Qs[(w * 16 + lr) * 64 + ks * 32 + lk * 8];
#pragma unroll
      for (int n = 0; n < 4; ++n) {
        s16x8 bk = *(const s16x8*)&Ks[(n * 16 + lr) * 64 + ks * 32 + lk * 8];
        s_acc[n] = __builtin_amdgcn_mfma_f32_16x16x32_bf16(aq, bk, s_acc[n], 0, 0, 0);
      }
    }
    // scale + mask; row max (C/D layout: col=l&15, row=(l>>4)*4+r2)
    float sv[4][4], pm[4];
#pragma unroll
    for (int r2 = 0; r2 < 4; ++r2) pm[r2] = -3.0e38f;
#pragma unroll
    for (int n = 0; n < 4; ++n)
#pragma unroll
      for (int r2 = 0; r2 < 4; ++r2) {
        float s = s_acc[n][r2] * 0.125f;
        const int qrow = w * 16 + lk * 4 + r2, kcol = n * 16 + lr;
        if (Ms[qrow * 64 + kcol]) s = -3.0e38f;
        sv[n][r2] = s;
        pm[r2] = fmaxf(pm[r2], s);
      }
#pragma unroll
    for (int d = 1; d < 16; d <<= 1)
#pragma unroll
      for (int r2 = 0; r2 < 4; ++r2) pm[r2] = fmaxf(pm[r2], __shfl_xor(pm[r2], d, 64));

    float resc[4], psum[4];
#pragma unroll
    for (int r2 = 0; r2 < 4; ++r2) {
      const float mnew = fmaxf(m_r[r2], pm[r2]);
      resc[r2] = __expf(m_r[r2] - mnew);
      m_r[r2] = mnew;
      psum[r2] = 0.f;
    }
#pragma unroll
    for (int n = 0; n < 4; ++n)
#pragma unroll
      for (int r2 = 0; r2 < 4; ++r2) {
        const float p = __expf(sv[n][r2] - m_r[r2]);   // masked -> exp(-huge) = 0
        psum[r2] += p;
        Ps[w][(lk * 4 + r2) * 64 + n * 16 + lr] = f2bf(p);
      }
#pragma unroll
    for (int d = 1; d < 16; d <<= 1)
#pragma unroll
      for (int r2 = 0; r2 < 4; ++r2) psum[r2] += __shfl_xor(psum[r2], d, 64);
#pragma unroll
    for (int r2 = 0; r2 < 4; ++r2) l_r[r2] = l_r[r2] * resc[r2] + psum[r2];
#pragma unroll
    for (int dn = 0; dn < 4; ++dn)
#pragma unroll
      for (int r2 = 0; r2 < 4; ++r2) acc_o[dn][r2] *= resc[r2];
    // PV: O += P @ V   (A frag = Ps row, B frag = Vts[d][n] contiguous in n)
#pragma unroll
    for (int ks = 0; ks < 2; ++ks) {
      s16x8 ap = *(const s16x8*)&Ps[w][lr * 64 + ks * 32 + lk * 8];
#pragma unroll
      for (int dn = 0; dn < 4; ++dn) {
        s16x8 bv = *(const s16x8*)&Vts[(dn * 16 + lr) * 64 + ks * 32 + lk * 8];
        acc_o[dn] = __builtin_amdgcn_mfma_f32_16x16x32_bf16(ap, bv, acc_o[dn], 0, 0, 0);
      }
    }
  }
  // epilogue: divide by softmax1 denominator, write [B,N,H*D] bf16
#pragma unroll
  for (int dn = 0; dn < 4; ++dn)
#pragma unroll
    for (int r2 = 0; r2 < 4; ++r2) {
      const int qrow = q0 + w * 16 + lk * 4 + r2;
      const int dcol = h * 64 + dn * 16 + lr;
      o_ws[(rowbase + qrow) * 1024 + dcol] = f2bf(acc_o[dn][r2] / l_r[r2]);
    }
}

// ---------------- launch ----------------
extern "C" void kernel_launch(void* const* d_in, const int* in_sizes, int n_in,
                              void* d_out, int out_size, void* d_ws, size_t ws_size,
                              hipStream_t stream) {
  const float* x      = (const float*)d_in[0];
  const void*  maskp  = d_in[1];
  const float* ln1_g  = (const float*)d_in[2];
  const float* ln1_b  = (const float*)d_in[3];
  const float* qkv_w  = (const float*)d_in[4];
  const float* qkv_b  = (const float*)d_in[5];
  const float* proj_w = (const float*)d_in[6];
  const float* proj_b = (const float*)d_in[7];
  const float* ln2_g  = (const float*)d_in[8];
  const float* ln2_b  = (const float*)d_in[9];
  const float* fc1_w  = (const float*)d_in[10];
  const float* fc1_b  = (const float*)d_in[11];
  const float* fc2_w  = (const float*)d_in[12];
  const float* fc2_b  = (const float*)d_in[13];
  float* out = (float*)d_out;

  char* ws = (char*)d_ws;
  int* flag             = (int*)ws;                                  // 256 B
  unsigned short* bufA  = (unsigned short*)(ws + 256);               // 33.6 MB: qkv, later mlp-mid
  unsigned short* bufH  = (unsigned short*)(ws + 256 + 33554432);    // 8.4 MB: h / h2
  unsigned short* bufO  = (unsigned short*)(ws + 256 + 33554432 + 8388608);        // 8.4 MB: attn out
  float* bufX1          = (float*)(ws + 256 + 33554432 + 2 * 8388608);             // 16.8 MB: x + attn
  unsigned short* bufW  = (unsigned short*)(ws + 256 + 33554432 + 2 * 8388608 + 16777216); // 8.4 MB: bf16 weights

  mask_detect<<<1, 256, 0, stream>>>((const unsigned char*)maskp, flag);
  ln_bf16<<<4096, 256, 0, stream>>>(x, ln1_g, ln1_b, bufH);
  f32_to_bf16<<<2048, 256, 0, stream>>>(qkv_w, bufW, 3072 * 1024);
  gemm_bt<0><<<dim3(24, 32), 256, 0, stream>>>(bufH, bufW, qkv_b, nullptr, bufA, 4096, 3072, 1024);
  attn_kernel<<<dim3(64, 16), 256, 0, stream>>>(bufA, maskp, flag, bufO);
  f32_to_bf16<<<2048, 256, 0, stream>>>(proj_w, bufW, 1024 * 1024);
  gemm_bt<2><<<dim3(8, 32), 256, 0, stream>>>(bufO, bufW, proj_b, x, bufX1, 4096, 1024, 1024);
  ln_bf16<<<4096, 256, 0, stream>>>(bufX1, ln2_g, ln2_b, bufH);
  f32_to_bf16<<<2048, 256, 0, stream>>>(fc1_w, bufW, 4096 * 1024);
  gemm_bt<1><<<dim3(32, 32), 256, 0, stream>>>(bufH, bufW, fc1_b, nullptr, bufA, 4096, 4096, 1024);
  f32_to_bf16<<<2048, 256, 0, stream>>>(fc2_w, bufW, 1024 * 4096);
  gemm_bt<2><<<dim3(8, 32), 256, 0, stream>>>(bufA, bufW, fc2_b, bufX1, out, 4096, 1024, 4096);
}

// Round 2
// 429.276 us; speedup vs baseline: 1.1188x; 1.1188x over previous
//
#include <hip/hip_runtime.h>
#include <hip/hip_bf16.h>
#include <cstdint>
#include <cstddef>

// ---------------- types & helpers ----------------
typedef __attribute__((ext_vector_type(4))) float f32x4;
typedef __attribute__((ext_vector_type(8))) short s16x8;       // 8 bf16 (4 VGPRs) MFMA frag
typedef __attribute__((ext_vector_type(4))) unsigned int u32x4;
typedef __attribute__((ext_vector_type(4))) unsigned short u16x4;

__device__ __forceinline__ unsigned short f2bf(float f) {
  union { float f; unsigned int u; } v; v.f = f;
  return (unsigned short)((v.u + 0x7fffu + ((v.u >> 16) & 1u)) >> 16);  // RNE
}

__device__ __forceinline__ void gll16(const void* g, void* l) {
  // async global->LDS, 16B per lane. LDS dest must be wave-uniform base + lane*16.
  __builtin_amdgcn_global_load_lds(
      (const __attribute__((address_space(1))) void*)g,
      (__attribute__((address_space(3))) void*)l, 16, 0, 0);
}

// ---------------- mask dtype detector ----------------
__global__ void mask_detect(const unsigned char* __restrict__ m, int* __restrict__ flag) {
  __shared__ int f;
  if (threadIdx.x == 0) f = 0;
  __syncthreads();
  unsigned int found = 0;
  for (int i = threadIdx.x * 16; i < 65536; i += 256 * 16) {
    u32x4 v = *(const u32x4*)(m + i);
    found |= (v.x & 0xFFFFFF00u) | (v.y & 0xFFFFFF00u) |
             (v.z & 0xFFFFFF00u) | (v.w & 0xFFFFFF00u);
  }
  if (found) atomicOr(&f, 1);
  __syncthreads();
  if (threadIdx.x == 0) *flag = f;
}

// ---------------- LayerNorm (fp32 in -> bf16 out), one row per block ----------------
__global__ __launch_bounds__(256)
void ln_bf16(const float* __restrict__ x, const float* __restrict__ g,
             const float* __restrict__ bta, unsigned short* __restrict__ out) {
  const int row = blockIdx.x;
  const int t = threadIdx.x;
  const float* xr = x + (size_t)row * 1024;
  f32x4 v = *(const f32x4*)(xr + t * 4);
  float s  = v.x + v.y + v.z + v.w;
  float sq = v.x * v.x + v.y * v.y + v.z * v.z + v.w * v.w;
#pragma unroll
  for (int d = 1; d < 64; d <<= 1) { s += __shfl_xor(s, d, 64); sq += __shfl_xor(sq, d, 64); }
  __shared__ float ss[4], ssq[4];
  const int w = t >> 6;
  if ((t & 63) == 0) { ss[w] = s; ssq[w] = sq; }
  __syncthreads();
  s  = ss[0] + ss[1] + ss[2] + ss[3];
  sq = ssq[0] + ssq[1] + ssq[2] + ssq[3];
  const float mu  = s * (1.0f / 1024.0f);
  const float var = sq * (1.0f / 1024.0f) - mu * mu;
  const float rs  = rsqrtf(var + 1e-5f);
  f32x4 gv = *(const f32x4*)(g + t * 4);
  f32x4 bv = *(const f32x4*)(bta + t * 4);
  u16x4 o;
  o.x = f2bf((v.x - mu) * rs * gv.x + bv.x);
  o.y = f2bf((v.y - mu) * rs * gv.y + bv.y);
  o.z = f2bf((v.z - mu) * rs * gv.z + bv.z);
  o.w = f2bf((v.w - mu) * rs * gv.w + bv.w);
  *(u16x4*)(out + (size_t)row * 1024 + t * 4) = o;
}

// ---------------- fp32 -> bf16 convert (fallback path) ----------------
__global__ __launch_bounds__(256)
void f32_to_bf16(const float* __restrict__ in, unsigned short* __restrict__ out, int n) {
  for (int i = (blockIdx.x * 256 + threadIdx.x) * 4; i < n; i += gridDim.x * 256 * 4) {
    f32x4 v = *(const f32x4*)(in + i);
    u16x4 o = { f2bf(v.x), f2bf(v.y), f2bf(v.z), f2bf(v.w) };
    *(u16x4*)(out + i) = o;
  }
}

// ---------------- merged weight convert (all 4 weights, one launch) ----------------
__global__ __launch_bounds__(256)
void convert_weights(const float* __restrict__ w0, const float* __restrict__ w1,
                     const float* __restrict__ w2, const float* __restrict__ w3,
                     unsigned short* __restrict__ o0, unsigned short* __restrict__ o1,
                     unsigned short* __restrict__ o2, unsigned short* __restrict__ o3) {
  // sizes: 3145728, 1048576, 4194304, 4194304
  const int gid = blockIdx.x * 256 + threadIdx.x;
  for (int i = gid * 4; i < 12582912; i += gridDim.x * 256 * 4) {
    const float* src; unsigned short* dst; int off;
    if (i < 3145728)      { src = w0; dst = o0; off = i; }
    else if (i < 4194304) { src = w1; dst = o1; off = i - 3145728; }
    else if (i < 8388608) { src = w2; dst = o2; off = i - 4194304; }
    else                  { src = w3; dst = o3; off = i - 8388608; }
    f32x4 v = *(const f32x4*)(src + off);
    u16x4 o = { f2bf(v.x), f2bf(v.y), f2bf(v.z), f2bf(v.w) };
    *(u16x4*)(dst + off) = o;
  }
}

// ---------------- BT-GEMM: C[M,N] = A[M,K] @ B[N,K]^T + bias, epilogues ----------------
// EPI 0: bf16 store. EPI 1: exact GELU -> bf16. EPI 2: + resid -> fp32.
// NW = n-frags per wave; BN = 32*NW (128 for wide outputs, 64 for N=1024 occupancy).
template<int EPI, int NW>
__global__ __launch_bounds__(256)
void gemm_bt(const unsigned short* __restrict__ A, const unsigned short* __restrict__ Bw,
             const float* __restrict__ bias, const float* __restrict__ resid,
             void* __restrict__ Cout, int M, int N, int K) {
  constexpr int BN = 32 * NW;
  __shared__ unsigned short As[128 * 64];
  __shared__ unsigned short Bs[BN * 64];
  const int tid = threadIdx.x;
  const int bx = blockIdx.x;          // col tile
  const int by = blockIdx.y;          // row tile
  const int w = tid >> 6, l = tid & 63;
  const int wr = w >> 1, wc = w & 1;
  const int lr = l & 15, lk = l >> 4;

  f32x4 acc[4][NW] = {};
  const int row0A = by * 128, row0B = bx * BN;

  for (int kt = 0; kt < K; kt += 64) {
#pragma unroll
    for (int it = 0; it < 4; ++it) {
      const int c = it * 256 + tid;
      const int r = c >> 3, c8 = (c & 7) * 8;
      gll16(A + (size_t)(row0A + r) * K + kt + c8, As + c * 8);
      if (it < NW)
        gll16(Bw + (size_t)(row0B + r) * K + kt + c8, Bs + c * 8);
    }
    asm volatile("s_waitcnt vmcnt(0)" ::: "memory");
    __syncthreads();
#pragma unroll
    for (int ks = 0; ks < 2; ++ks) {
      s16x8 af[4], bfr[NW];
#pragma unroll
      for (int m = 0; m < 4; ++m)
        af[m] = *(const s16x8*)&As[(wr * 64 + m * 16 + lr) * 64 + ks * 32 + lk * 8];
#pragma unroll
      for (int n = 0; n < NW; ++n)
        bfr[n] = *(const s16x8*)&Bs[(wc * (BN / 2) + n * 16 + lr) * 64 + ks * 32 + lk * 8];
#pragma unroll
      for (int m = 0; m < 4; ++m)
#pragma unroll
        for (int n = 0; n < NW; ++n)
          acc[m][n] = __builtin_amdgcn_mfma_f32_16x16x32_bf16(af[m], bfr[n], acc[m][n], 0, 0, 0);
    }
    __syncthreads();
  }
#pragma unroll
  for (int m = 0; m < 4; ++m) {
#pragma unroll
    for (int n = 0; n < NW; ++n) {
      const int col = bx * BN + wc * (BN / 2) + n * 16 + lr;
      const float bval = bias[col];
#pragma unroll
      for (int r2 = 0; r2 < 4; ++r2) {
        const int row = by * 128 + wr * 64 + m * 16 + lk * 4 + r2;
        float vv = acc[m][n][r2] + bval;
        const size_t idx = (size_t)row * N + col;
        if (EPI == 0) {
          ((unsigned short*)Cout)[idx] = f2bf(vv);
        } else if (EPI == 1) {
          float ge = 0.5f * vv * (1.0f + erff(vv * 0.70710678118f));
          ((unsigned short*)Cout)[idx] = f2bf(ge);
        } else {
          ((float*)Cout)[idx] = vv + resid[idx];
        }
      }
    }
  }
}

// ---------------- flash attention v2: swapped QK^T, swizzled LDS, softmax1 ----------------
// qkv: [4096, 3072] bf16. grid: 1024 linear blocks (XCD-chunk swizzled).
// 4 waves/block, each wave owns 16 Q rows; KV tiles of 64.
__global__ __launch_bounds__(256, 4)
void attn2(const unsigned short* __restrict__ qkv, const void* __restrict__ maskp,
           const int* __restrict__ flag, unsigned short* __restrict__ o_ws) {
  __shared__ unsigned short Qs[64 * 64];   // swizzled
  __shared__ unsigned short Ks[64 * 64];   // swizzled
  __shared__ unsigned short Vts[64 * 64];  // transposed [d][n], swizzled
  __shared__ unsigned short Ps[4][16 * 64];// per-wave P, swizzled

  const int tid = threadIdx.x;
  // XCD-chunk swizzle: 1024 blocks, 8 XCDs -> contiguous 128-block chunks per XCD.
  const int orig = blockIdx.x;
  const int swzb = (orig & 7) * 128 + (orig >> 3);
  const int bh = swzb >> 4, qt = swzb & 15;
  const int b = bh >> 4, h = bh & 15;
  const int q0 = qt * 64;
  const int w = tid >> 6, l = tid & 63;
  const int lr = l & 15, lk = l >> 4;
  const size_t rowbase = (size_t)b * 1024;
  const int qoff = h * 64, koff = 1024 + h * 64, voff = 2048 + h * 64;

  // Q staging (swizzled source -> linear LDS; read with XOR((row&7)<<4))
#pragma unroll
  for (int it = 0; it < 2; ++it) {
    const int c = it * 256 + tid;
    const int r = c >> 3, j0 = c & 7;
    const int jsrc = j0 ^ (r & 7);
    gll16(qkv + (rowbase + q0 + r) * 3072 + qoff + jsrc * 8, Qs + c * 8);
  }
  const int mask_is_byte = *flag;
  const int qrow_g = q0 + w * 16 + lr;                   // this lane's q row
  const unsigned char* mrow_b = (const unsigned char*)maskp + ((size_t)b * 1024 + qrow_g) * 1024;
  const int* mrow_i = (const int*)maskp + ((size_t)b * 1024 + qrow_g) * 1024;

  const int np = tid & 31, dg = tid >> 5;                // V-stage role: rows 2np,2np+1, d-group dg

  float m_r = 0.f, l_r = 1.f;                            // softmax1 seed: implicit 0 logit
  f32x4 acc_o[4] = {};

  for (int nt = 0; nt < 16; ++nt) {
    const int n0 = nt * 64;
    // --- early VMEM issues (latency hides under staging+barrier) ---
    const unsigned short* vsrc = qkv + (rowbase + n0 + 2 * np) * 3072 + voff + dg * 8;
    u32x4 va = *(const u32x4*)vsrc;
    u32x4 vb = *(const u32x4*)(vsrc + 3072);
    unsigned int mb[4];
    if (mask_is_byte) {
#pragma unroll
      for (int n = 0; n < 4; ++n)
        mb[n] = *(const unsigned int*)(mrow_b + n0 + n * 16 + lk * 4);
    } else {
#pragma unroll
      for (int n = 0; n < 4; ++n) {
        u32x4 t4 = *(const u32x4*)(mrow_i + n0 + n * 16 + lk * 4);
        mb[n] = (t4.x ? 1u : 0u) | (t4.y ? 0x100u : 0u) |
                (t4.z ? 0x10000u : 0u) | (t4.w ? 0x1000000u : 0u);
      }
    }
    __syncthreads();          // previous tile fully consumed
    // K staging (pre-swizzled source)
#pragma unroll
    for (int it = 0; it < 2; ++it) {
      const int c = it * 256 + tid;
      const int r = c >> 3, j0 = c & 7;
      const int jsrc = j0 ^ (r & 7);
      gll16(qkv + (rowbase + n0 + r) * 3072 + koff + jsrc * 8, Ks + c * 8);
    }
    // V transposed paired writes (swizzled): Vts[d][2np..2np+1]
    {
      const unsigned short* ea = (const unsigned short*)&va;
      const unsigned short* eb = (const unsigned short*)&vb;
#pragma unroll
      for (int j = 0; j < 8; ++j) {
        const int d = dg * 8 + j;
        const unsigned int pv = (unsigned int)ea[j] | ((unsigned int)eb[j] << 16);
        const int byte = (d * 128 + np * 4) ^ ((d & 7) << 4);
        *(unsigned int*)((char*)Vts + byte) = pv;
      }
    }
    asm volatile("s_waitcnt vmcnt(0)" ::: "memory");
    __syncthreads();

    // --- QK^T swapped: D[k_in_tile, q] = sum_d K[k][d] Q[q][d] ---
    f32x4 s_acc[4] = {};
#pragma unroll
    for (int ks = 0; ks < 2; ++ks) {
      const int cb = ks * 64 + lk * 16;
      const s16x8 qf = *(const s16x8*)((char*)Qs + (((w * 16 + lr) * 128 + cb) ^ ((lr & 7) << 4)));
#pragma unroll
      for (int n = 0; n < 4; ++n) {
        const s16x8 kf = *(const s16x8*)((char*)Ks + (((n * 16 + lr) * 128 + cb) ^ ((lr & 7) << 4)));
        s_acc[n] = __builtin_amdgcn_mfma_f32_16x16x32_bf16(kf, qf, s_acc[n], 0, 0, 0);
      }
    }
    // --- lane-local softmax row (q = w*16+lr); k = n*16 + lk*4 + r2 ---
    float pmax = -3.0e38f;
#pragma unroll
    for (int n = 0; n < 4; ++n)
#pragma unroll
      for (int r2 = 0; r2 < 4; ++r2) {
        float s = s_acc[n][r2] * 0.125f;
        if ((mb[n] >> (8 * r2)) & 0xff) s = -3.0e38f;
        s_acc[n][r2] = s;
        pmax = fmaxf(pmax, s);
      }
    pmax = fmaxf(pmax, __shfl_xor(pmax, 16, 64));
    pmax = fmaxf(pmax, __shfl_xor(pmax, 32, 64));
    const float mnew = fmaxf(m_r, pmax);
    const float resc = __expf(m_r - mnew);
    m_r = mnew;
    float psum = 0.f;
    unsigned int pk[4][2];
#pragma unroll
    for (int n = 0; n < 4; ++n)
#pragma unroll
      for (int h2 = 0; h2 < 2; ++h2) {
        const float p0 = __expf(s_acc[n][2 * h2]     - mnew);
        const float p1 = __expf(s_acc[n][2 * h2 + 1] - mnew);
        psum += p0 + p1;
        pk[n][h2] = (unsigned int)f2bf(p0) | ((unsigned int)f2bf(p1) << 16);
      }
    psum += __shfl_xor(psum, 16, 64);
    psum += __shfl_xor(psum, 32, 64);
    l_r = l_r * resc + psum;
    // P -> per-wave LDS (swizzled b32 pairs)
    char* psw = (char*)&Ps[w][0];
#pragma unroll
    for (int n = 0; n < 4; ++n)
#pragma unroll
      for (int h2 = 0; h2 < 2; ++h2) {
        const int byte = (lr * 128 + n * 32 + lk * 8 + h2 * 4) ^ ((lr & 7) << 4);
        *(unsigned int*)(psw + byte) = pk[n][h2];
      }
    // rescale acc_o: my output rows are q' = lk*4+r2 -> fetch resc from lane lr'=q'
    float rs4[4];
#pragma unroll
    for (int r2 = 0; r2 < 4; ++r2)
      rs4[r2] = __shfl(resc, (l & 48) | (lk * 4 + r2), 64);
#pragma unroll
    for (int dn = 0; dn < 4; ++dn)
#pragma unroll
      for (int r2 = 0; r2 < 4; ++r2) acc_o[dn][r2] *= rs4[r2];
    // --- PV: O[q,d] += P[q,k] V[k,d] ---
#pragma unroll
    for (int ks = 0; ks < 2; ++ks) {
      const int cb = ks * 64 + lk * 16;
      const s16x8 ap = *(const s16x8*)(psw + ((lr * 128 + cb) ^ ((lr & 7) << 4)));
#pragma unroll
      for (int dn = 0; dn < 4; ++dn) {
        const s16x8 bv = *(const s16x8*)((char*)Vts + (((dn * 16 + lr) * 128 + cb) ^ ((lr & 7) << 4)));
        acc_o[dn] = __builtin_amdgcn_mfma_f32_16x16x32_bf16(ap, bv, acc_o[dn], 0, 0, 0);
      }
    }
  }
  // epilogue: divide by softmax1 denom (bpermute l for my output rows), write bf16
  const float linv = 1.0f / l_r;
  float li4[4];
#pragma unroll
  for (int r2 = 0; r2 < 4; ++r2)
    li4[r2] = __shfl(linv, (l & 48) | (lk * 4 + r2), 64);
#pragma unroll
  for (int dn = 0; dn < 4; ++dn)
#pragma unroll
    for (int r2 = 0; r2 < 4; ++r2) {
      const int qrow = q0 + w * 16 + lk * 4 + r2;
      const int dcol = h * 64 + dn * 16 + lr;
      o_ws[(rowbase + qrow) * 1024 + dcol] = f2bf(acc_o[dn][r2] * li4[r2]);
    }
}

// ---------------- launch ----------------
extern "C" void kernel_launch(void* const* d_in, const int* in_sizes, int n_in,
                              void* d_out, int out_size, void* d_ws, size_t ws_size,
                              hipStream_t stream) {
  const float* x      = (const float*)d_in[0];
  const void*  maskp  = d_in[1];
  const float* ln1_g  = (const float*)d_in[2];
  const float* ln1_b  = (const float*)d_in[3];
  const float* qkv_w  = (const float*)d_in[4];
  const float* qkv_b  = (const float*)d_in[5];
  const float* proj_w = (const float*)d_in[6];
  const float* proj_b = (const float*)d_in[7];
  const float* ln2_g  = (const float*)d_in[8];
  const float* ln2_b  = (const float*)d_in[9];
  const float* fc1_w  = (const float*)d_in[10];
  const float* fc1_b  = (const float*)d_in[11];
  const float* fc2_w  = (const float*)d_in[12];
  const float* fc2_b  = (const float*)d_in[13];
  float* out = (float*)d_out;

  char* ws = (char*)d_ws;
  int* flag            = (int*)ws;                                   // 256 B
  unsigned short* bufA = (unsigned short*)(ws + 256);                // 33.6 MB
  unsigned short* bufH = (unsigned short*)(ws + 256 + 33554432);     // 8.4 MB
  unsigned short* bufO = (unsigned short*)(ws + 256 + 33554432 + 8388608);          // 8.4 MB
  float* bufX1         = (float*)(ws + 256 + 33554432 + 2 * 8388608);               // 16.8 MB
  char* wbase          = ws + 256 + 33554432 + 2 * 8388608 + 16777216;

  mask_detect<<<1, 256, 0, stream>>>((const unsigned char*)maskp, flag);

  const bool bigws = ws_size >= (size_t)92274944;
  if (bigws) {
    unsigned short* W0 = (unsigned short*)wbase;                 // qkv  6.3 MB
    unsigned short* W1 = (unsigned short*)(wbase + 6291456);     // proj 2.1 MB
    unsigned short* W2 = (unsigned short*)(wbase + 8388608);     // fc1  8.4 MB
    unsigned short* W3 = (unsigned short*)(wbase + 16777216);    // fc2  8.4 MB
    convert_weights<<<4096, 256, 0, stream>>>(qkv_w, proj_w, fc1_w, fc2_w, W0, W1, W2, W3);
    ln_bf16<<<4096, 256, 0, stream>>>(x, ln1_g, ln1_b, bufH);
    gemm_bt<0, 4><<<dim3(24, 32), 256, 0, stream>>>(bufH, W0, qkv_b, nullptr, bufA, 4096, 3072, 1024);
    attn2<<<1024, 256, 0, stream>>>(bufA, maskp, flag, bufO);
    gemm_bt<2, 2><<<dim3(16, 32), 256, 0, stream>>>(bufO, W1, proj_b, x, bufX1, 4096, 1024, 1024);
    ln_bf16<<<4096, 256, 0, stream>>>(bufX1, ln2_g, ln2_b, bufH);
    gemm_bt<1, 4><<<dim3(32, 32), 256, 0, stream>>>(bufH, W2, fc1_b, nullptr, bufA, 4096, 4096, 1024);
    gemm_bt<2, 2><<<dim3(16, 32), 256, 0, stream>>>(bufA, W3, fc2_b, bufX1, out, 4096, 1024, 4096);
  } else {
    unsigned short* bufW = (unsigned short*)wbase;               // shared 8.4 MB
    ln_bf16<<<4096, 256, 0, stream>>>(x, ln1_g, ln1_b, bufH);
    f32_to_bf16<<<2048, 256, 0, stream>>>(qkv_w, bufW, 3072 * 1024);
    gemm_bt<0, 4><<<dim3(24, 32), 256, 0, stream>>>(bufH, bufW, qkv_b, nullptr, bufA, 4096, 3072, 1024);
    attn2<<<1024, 256, 0, stream>>>(bufA, maskp, flag, bufO);
    f32_to_bf16<<<2048, 256, 0, stream>>>(proj_w, bufW, 1024 * 1024);
    gemm_bt<2, 2><<<dim3(16, 32), 256, 0, stream>>>(bufO, bufW, proj_b, x, bufX1, 4096, 1024, 1024);
    ln_bf16<<<4096, 256, 0, stream>>>(bufX1, ln2_g, ln2_b, bufH);
    f32_to_bf16<<<2048, 256, 0, stream>>>(fc1_w, bufW, 4096 * 1024);
    gemm_bt<1, 4><<<dim3(32, 32), 256, 0, stream>>>(bufH, bufW, fc1_b, nullptr, bufA, 4096, 4096, 1024);
    f32_to_bf16<<<2048, 256, 0, stream>>>(fc2_w, bufW, 1024 * 4096);
    gemm_bt<2, 2><<<dim3(16, 32), 256, 0, stream>>>(bufA, bufW, fc2_b, bufX1, out, 4096, 1024, 4096);
  }
}

// Round 3
// 413.668 us; speedup vs baseline: 1.1610x; 1.0377x over previous
//
#include <hip/hip_runtime.h>
#include <hip/hip_bf16.h>
#include <cstdint>
#include <cstddef>

// ---------------- types & helpers ----------------
typedef __attribute__((ext_vector_type(4))) float f32x4;
typedef __attribute__((ext_vector_type(8))) short s16x8;       // 8 bf16 (4 VGPRs) MFMA frag
typedef __attribute__((ext_vector_type(4))) unsigned int u32x4;
typedef __attribute__((ext_vector_type(4))) unsigned short u16x4;

__device__ __forceinline__ unsigned short f2bf(float f) {
  union { float f; unsigned int u; } v; v.f = f;
  return (unsigned short)((v.u + 0x7fffu + ((v.u >> 16) & 1u)) >> 16);  // RNE
}

__device__ __forceinline__ void gll16(const void* g, void* l) {
  // async global->LDS, 16B per lane. LDS dest must be wave-uniform base + lane*16.
  __builtin_amdgcn_global_load_lds(
      (const __attribute__((address_space(1))) void*)g,
      (__attribute__((address_space(3))) void*)l, 16, 0, 0);
}

// ---------------- mask dtype detector ----------------
__global__ void mask_detect(const unsigned char* __restrict__ m, int* __restrict__ flag) {
  __shared__ int f;
  if (threadIdx.x == 0) f = 0;
  __syncthreads();
  unsigned int found = 0;
  for (int i = threadIdx.x * 16; i < 65536; i += 256 * 16) {
    u32x4 v = *(const u32x4*)(m + i);
    found |= (v.x & 0xFFFFFF00u) | (v.y & 0xFFFFFF00u) |
             (v.z & 0xFFFFFF00u) | (v.w & 0xFFFFFF00u);
  }
  if (found) atomicOr(&f, 1);
  __syncthreads();
  if (threadIdx.x == 0) *flag = f;
}

// ---------------- LayerNorm (fp32 in -> bf16 out), one row per block ----------------
__global__ __launch_bounds__(256)
void ln_bf16(const float* __restrict__ x, const float* __restrict__ g,
             const float* __restrict__ bta, unsigned short* __restrict__ out) {
  const int row = blockIdx.x;
  const int t = threadIdx.x;
  const float* xr = x + (size_t)row * 1024;
  f32x4 v = *(const f32x4*)(xr + t * 4);
  float s  = v.x + v.y + v.z + v.w;
  float sq = v.x * v.x + v.y * v.y + v.z * v.z + v.w * v.w;
#pragma unroll
  for (int d = 1; d < 64; d <<= 1) { s += __shfl_xor(s, d, 64); sq += __shfl_xor(sq, d, 64); }
  __shared__ float ss[4], ssq[4];
  const int w = t >> 6;
  if ((t & 63) == 0) { ss[w] = s; ssq[w] = sq; }
  __syncthreads();
  s  = ss[0] + ss[1] + ss[2] + ss[3];
  sq = ssq[0] + ssq[1] + ssq[2] + ssq[3];
  const float mu  = s * (1.0f / 1024.0f);
  const float var = sq * (1.0f / 1024.0f) - mu * mu;
  const float rs  = rsqrtf(var + 1e-5f);
  f32x4 gv = *(const f32x4*)(g + t * 4);
  f32x4 bv = *(const f32x4*)(bta + t * 4);
  u16x4 o;
  o.x = f2bf((v.x - mu) * rs * gv.x + bv.x);
  o.y = f2bf((v.y - mu) * rs * gv.y + bv.y);
  o.z = f2bf((v.z - mu) * rs * gv.z + bv.z);
  o.w = f2bf((v.w - mu) * rs * gv.w + bv.w);
  *(u16x4*)(out + (size_t)row * 1024 + t * 4) = o;
}

// ---------------- fp32 -> bf16 convert (fallback path) ----------------
__global__ __launch_bounds__(256)
void f32_to_bf16(const float* __restrict__ in, unsigned short* __restrict__ out, int n) {
  for (int i = (blockIdx.x * 256 + threadIdx.x) * 4; i < n; i += gridDim.x * 256 * 4) {
    f32x4 v = *(const f32x4*)(in + i);
    u16x4 o = { f2bf(v.x), f2bf(v.y), f2bf(v.z), f2bf(v.w) };
    *(u16x4*)(out + i) = o;
  }
}

// ---------------- merged weight convert (all 4 weights, one launch) ----------------
__global__ __launch_bounds__(256)
void convert_weights(const float* __restrict__ w0, const float* __restrict__ w1,
                     const float* __restrict__ w2, const float* __restrict__ w3,
                     unsigned short* __restrict__ o0, unsigned short* __restrict__ o1,
                     unsigned short* __restrict__ o2, unsigned short* __restrict__ o3) {
  const int gid = blockIdx.x * 256 + threadIdx.x;
  for (int i = gid * 4; i < 12582912; i += gridDim.x * 256 * 4) {
    const float* src; unsigned short* dst; int off;
    if (i < 3145728)      { src = w0; dst = o0; off = i; }
    else if (i < 4194304) { src = w1; dst = o1; off = i - 3145728; }
    else if (i < 8388608) { src = w2; dst = o2; off = i - 4194304; }
    else                  { src = w3; dst = o3; off = i - 8388608; }
    f32x4 v = *(const f32x4*)(src + off);
    u16x4 o = { f2bf(v.x), f2bf(v.y), f2bf(v.z), f2bf(v.w) };
    *(u16x4*)(dst + off) = o;
  }
}

// ---------------- BT-GEMM v2: double-buffered LDS, early-issue staging ----------------
// C[M,N] = A[M,K] @ B[N,K]^T + bias. EPI 0: bf16. EPI 1: fast GELU -> bf16. EPI 2: +resid -> fp32.
// 128xBN tile, BK=64, 256 threads (2x2 waves). One vmcnt(0)+barrier per K-step (T3-min).
template<int EPI, int NW>
__global__ __launch_bounds__(256)
void gemm_bt(const unsigned short* __restrict__ A, const unsigned short* __restrict__ Bw,
             const float* __restrict__ bias, const float* __restrict__ resid,
             void* __restrict__ Cout, int M, int N, int K) {
  constexpr int BN = 32 * NW;
  __shared__ unsigned short As[2][128 * 64];
  __shared__ unsigned short Bs[2][BN * 64];
  const int tid = threadIdx.x;
  const int bx = blockIdx.x;          // col tile
  const int by = blockIdx.y;          // row tile
  const int w = tid >> 6, l = tid & 63;
  const int wr = w >> 1, wc = w & 1;
  const int lr = l & 15, lk = l >> 4;

  f32x4 acc[4][NW] = {};
  const int row0A = by * 128, row0B = bx * BN;

  // per-thread staging coords (c = it*256+tid -> row c>>3, 16B chunk c&7)
  auto stage = [&](int buf, int kt) {
#pragma unroll
    for (int it = 0; it < 4; ++it) {
      const int c = it * 256 + tid;
      const int r = c >> 3, c8 = (c & 7) * 8;
      gll16(A + (size_t)(row0A + r) * K + kt + c8, &As[buf][c * 8]);
      if (it < NW)
        gll16(Bw + (size_t)(row0B + r) * K + kt + c8, &Bs[buf][c * 8]);
    }
  };

  stage(0, 0);
  asm volatile("s_waitcnt vmcnt(0)" ::: "memory");
  __syncthreads();

  const int nsteps = K >> 6;
  for (int t = 0; t < nsteps; ++t) {
    const int cur = t & 1;
    if (t + 1 < nsteps) stage(cur ^ 1, (t + 1) * 64);   // overlaps with ds_read+MFMA below
    const unsigned short* Ac = As[cur];
    const unsigned short* Bc = Bs[cur];
#pragma unroll
    for (int ks = 0; ks < 2; ++ks) {
      s16x8 af[4], bfr[NW];
#pragma unroll
      for (int m = 0; m < 4; ++m)
        af[m] = *(const s16x8*)&Ac[(wr * 64 + m * 16 + lr) * 64 + ks * 32 + lk * 8];
#pragma unroll
      for (int n = 0; n < NW; ++n)
        bfr[n] = *(const s16x8*)&Bc[(wc * (BN / 2) + n * 16 + lr) * 64 + ks * 32 + lk * 8];
#pragma unroll
      for (int m = 0; m < 4; ++m)
#pragma unroll
        for (int n = 0; n < NW; ++n)
          acc[m][n] = __builtin_amdgcn_mfma_f32_16x16x32_bf16(af[m], bfr[n], acc[m][n], 0, 0, 0);
    }
    if (t + 1 < nsteps) {
      asm volatile("s_waitcnt vmcnt(0)" ::: "memory");  // next tile landed
      __syncthreads();                                  // all waves done reading cur
    }
  }
#pragma unroll
  for (int m = 0; m < 4; ++m) {
#pragma unroll
    for (int n = 0; n < NW; ++n) {
      const int col = bx * BN + wc * (BN / 2) + n * 16 + lr;
      const float bval = bias[col];
#pragma unroll
      for (int r2 = 0; r2 < 4; ++r2) {
        const int row = by * 128 + wr * 64 + m * 16 + lk * 4 + r2;
        float vv = acc[m][n][r2] + bval;
        const size_t idx = (size_t)row * N + col;
        if (EPI == 0) {
          ((unsigned short*)Cout)[idx] = f2bf(vv);
        } else if (EPI == 1) {
          // tanh-form GELU via sigmoid: 0.5v(1+tanh(u)) = v*sigmoid(2u), |err vs erf| ~1e-3
          const float t2 = vv * (1.5957691216f + 0.0713548163f * vv * vv);  // 2u
          const float ge = vv / (1.0f + __expf(-t2));
          ((unsigned short*)Cout)[idx] = f2bf(ge);
        } else {
          ((float*)Cout)[idx] = vv + resid[idx];
        }
      }
    }
  }
}

// ---------------- flash attention v2: swapped QK^T, swizzled LDS, softmax1 ----------------
// qkv: [4096, 3072] bf16. grid: 1024 linear blocks (XCD-chunk swizzled).
// 4 waves/block, each wave owns 16 Q rows; KV tiles of 64.
__global__ __launch_bounds__(256, 4)
void attn2(const unsigned short* __restrict__ qkv, const void* __restrict__ maskp,
           const int* __restrict__ flag, unsigned short* __restrict__ o_ws) {
  __shared__ unsigned short Qs[64 * 64];   // swizzled
  __shared__ unsigned short Ks[64 * 64];   // swizzled
  __shared__ unsigned short Vts[64 * 64];  // transposed [d][n], swizzled
  __shared__ unsigned short Ps[4][16 * 64];// per-wave P, swizzled

  const int tid = threadIdx.x;
  const int orig = blockIdx.x;
  const int swzb = (orig & 7) * 128 + (orig >> 3);
  const int bh = swzb >> 4, qt = swzb & 15;
  const int b = bh >> 4, h = bh & 15;
  const int q0 = qt * 64;
  const int w = tid >> 6, l = tid & 63;
  const int lr = l & 15, lk = l >> 4;
  const size_t rowbase = (size_t)b * 1024;
  const int qoff = h * 64, koff = 1024 + h * 64, voff = 2048 + h * 64;

  // Q staging (swizzled source -> linear LDS; read with XOR((row&7)<<4))
#pragma unroll
  for (int it = 0; it < 2; ++it) {
    const int c = it * 256 + tid;
    const int r = c >> 3, j0 = c & 7;
    const int jsrc = j0 ^ (r & 7);
    gll16(qkv + (rowbase + q0 + r) * 3072 + qoff + jsrc * 8, Qs + c * 8);
  }
  const int mask_is_byte = *flag;
  const int qrow_g = q0 + w * 16 + lr;
  const unsigned char* mrow_b = (const unsigned char*)maskp + ((size_t)b * 1024 + qrow_g) * 1024;
  const int* mrow_i = (const int*)maskp + ((size_t)b * 1024 + qrow_g) * 1024;

  const int np = tid & 31, dg = tid >> 5;

  float m_r = 0.f, l_r = 1.f;
  f32x4 acc_o[4] = {};

  for (int nt = 0; nt < 16; ++nt) {
    const int n0 = nt * 64;
    const unsigned short* vsrc = qkv + (rowbase + n0 + 2 * np) * 3072 + voff + dg * 8;
    u32x4 va = *(const u32x4*)vsrc;
    u32x4 vb = *(const u32x4*)(vsrc + 3072);
    unsigned int mb[4];
    if (mask_is_byte) {
#pragma unroll
      for (int n = 0; n < 4; ++n)
        mb[n] = *(const unsigned int*)(mrow_b + n0 + n * 16 + lk * 4);
    } else {
#pragma unroll
      for (int n = 0; n < 4; ++n) {
        u32x4 t4 = *(const u32x4*)(mrow_i + n0 + n * 16 + lk * 4);
        mb[n] = (t4.x ? 1u : 0u) | (t4.y ? 0x100u : 0u) |
                (t4.z ? 0x10000u : 0u) | (t4.w ? 0x1000000u : 0u);
      }
    }
    __syncthreads();
#pragma unroll
    for (int it = 0; it < 2; ++it) {
      const int c = it * 256 + tid;
      const int r = c >> 3, j0 = c & 7;
      const int jsrc = j0 ^ (r & 7);
      gll16(qkv + (rowbase + n0 + r) * 3072 + koff + jsrc * 8, Ks + c * 8);
    }
    {
      const unsigned short* ea = (const unsigned short*)&va;
      const unsigned short* eb = (const unsigned short*)&vb;
#pragma unroll
      for (int j = 0; j < 8; ++j) {
        const int d = dg * 8 + j;
        const unsigned int pv = (unsigned int)ea[j] | ((unsigned int)eb[j] << 16);
        const int byte = (d * 128 + np * 4) ^ ((d & 7) << 4);
        *(unsigned int*)((char*)Vts + byte) = pv;
      }
    }
    asm volatile("s_waitcnt vmcnt(0)" ::: "memory");
    __syncthreads();

    f32x4 s_acc[4] = {};
#pragma unroll
    for (int ks = 0; ks < 2; ++ks) {
      const int cb = ks * 64 + lk * 16;
      const s16x8 qf = *(const s16x8*)((char*)Qs + (((w * 16 + lr) * 128 + cb) ^ ((lr & 7) << 4)));
#pragma unroll
      for (int n = 0; n < 4; ++n) {
        const s16x8 kf = *(const s16x8*)((char*)Ks + (((n * 16 + lr) * 128 + cb) ^ ((lr & 7) << 4)));
        s_acc[n] = __builtin_amdgcn_mfma_f32_16x16x32_bf16(kf, qf, s_acc[n], 0, 0, 0);
      }
    }
    float pmax = -3.0e38f;
#pragma unroll
    for (int n = 0; n < 4; ++n)
#pragma unroll
      for (int r2 = 0; r2 < 4; ++r2) {
        float s = s_acc[n][r2] * 0.125f;
        if ((mb[n] >> (8 * r2)) & 0xff) s = -3.0e38f;
        s_acc[n][r2] = s;
        pmax = fmaxf(pmax, s);
      }
    pmax = fmaxf(pmax, __shfl_xor(pmax, 16, 64));
    pmax = fmaxf(pmax, __shfl_xor(pmax, 32, 64));
    const float mnew = fmaxf(m_r, pmax);
    const float resc = __expf(m_r - mnew);
    m_r = mnew;
    float psum = 0.f;
    unsigned int pk[4][2];
#pragma unroll
    for (int n = 0; n < 4; ++n)
#pragma unroll
      for (int h2 = 0; h2 < 2; ++h2) {
        const float p0 = __expf(s_acc[n][2 * h2]     - mnew);
        const float p1 = __expf(s_acc[n][2 * h2 + 1] - mnew);
        psum += p0 + p1;
        pk[n][h2] = (unsigned int)f2bf(p0) | ((unsigned int)f2bf(p1) << 16);
      }
    psum += __shfl_xor(psum, 16, 64);
    psum += __shfl_xor(psum, 32, 64);
    l_r = l_r * resc + psum;
    char* psw = (char*)&Ps[w][0];
#pragma unroll
    for (int n = 0; n < 4; ++n)
#pragma unroll
      for (int h2 = 0; h2 < 2; ++h2) {
        const int byte = (lr * 128 + n * 32 + lk * 8 + h2 * 4) ^ ((lr & 7) << 4);
        *(unsigned int*)(psw + byte) = pk[n][h2];
      }
    float rs4[4];
#pragma unroll
    for (int r2 = 0; r2 < 4; ++r2)
      rs4[r2] = __shfl(resc, (l & 48) | (lk * 4 + r2), 64);
#pragma unroll
    for (int dn = 0; dn < 4; ++dn)
#pragma unroll
      for (int r2 = 0; r2 < 4; ++r2) acc_o[dn][r2] *= rs4[r2];
#pragma unroll
    for (int ks = 0; ks < 2; ++ks) {
      const int cb = ks * 64 + lk * 16;
      const s16x8 ap = *(const s16x8*)(psw + ((lr * 128 + cb) ^ ((lr & 7) << 4)));
#pragma unroll
      for (int dn = 0; dn < 4; ++dn) {
        const s16x8 bv = *(const s16x8*)((char*)Vts + (((dn * 16 + lr) * 128 + cb) ^ ((lr & 7) << 4)));
        acc_o[dn] = __builtin_amdgcn_mfma_f32_16x16x32_bf16(ap, bv, acc_o[dn], 0, 0, 0);
      }
    }
  }
  const float linv = 1.0f / l_r;
  float li4[4];
#pragma unroll
  for (int r2 = 0; r2 < 4; ++r2)
    li4[r2] = __shfl(linv, (l & 48) | (lk * 4 + r2), 64);
#pragma unroll
  for (int dn = 0; dn < 4; ++dn)
#pragma unroll
    for (int r2 = 0; r2 < 4; ++r2) {
      const int qrow = q0 + w * 16 + lk * 4 + r2;
      const int dcol = h * 64 + dn * 16 + lr;
      o_ws[(rowbase + qrow) * 1024 + dcol] = f2bf(acc_o[dn][r2] * li4[r2]);
    }
}

// ---------------- launch ----------------
extern "C" void kernel_launch(void* const* d_in, const int* in_sizes, int n_in,
                              void* d_out, int out_size, void* d_ws, size_t ws_size,
                              hipStream_t stream) {
  const float* x      = (const float*)d_in[0];
  const void*  maskp  = d_in[1];
  const float* ln1_g  = (const float*)d_in[2];
  const float* ln1_b  = (const float*)d_in[3];
  const float* qkv_w  = (const float*)d_in[4];
  const float* qkv_b  = (const float*)d_in[5];
  const float* proj_w = (const float*)d_in[6];
  const float* proj_b = (const float*)d_in[7];
  const float* ln2_g  = (const float*)d_in[8];
  const float* ln2_b  = (const float*)d_in[9];
  const float* fc1_w  = (const float*)d_in[10];
  const float* fc1_b  = (const float*)d_in[11];
  const float* fc2_w  = (const float*)d_in[12];
  const float* fc2_b  = (const float*)d_in[13];
  float* out = (float*)d_out;

  char* ws = (char*)d_ws;
  int* flag            = (int*)ws;                                   // 256 B
  unsigned short* bufA = (unsigned short*)(ws + 256);                // 33.6 MB
  unsigned short* bufH = (unsigned short*)(ws + 256 + 33554432);     // 8.4 MB
  unsigned short* bufO = (unsigned short*)(ws + 256 + 33554432 + 8388608);          // 8.4 MB
  float* bufX1         = (float*)(ws + 256 + 33554432 + 2 * 8388608);               // 16.8 MB
  char* wbase          = ws + 256 + 33554432 + 2 * 8388608 + 16777216;

  mask_detect<<<1, 256, 0, stream>>>((const unsigned char*)maskp, flag);

  const bool bigws = ws_size >= (size_t)92274944;
  if (bigws) {
    unsigned short* W0 = (unsigned short*)wbase;                 // qkv  6.3 MB
    unsigned short* W1 = (unsigned short*)(wbase + 6291456);     // proj 2.1 MB
    unsigned short* W2 = (unsigned short*)(wbase + 8388608);     // fc1  8.4 MB
    unsigned short* W3 = (unsigned short*)(wbase + 16777216);    // fc2  8.4 MB
    convert_weights<<<4096, 256, 0, stream>>>(qkv_w, proj_w, fc1_w, fc2_w, W0, W1, W2, W3);
    ln_bf16<<<4096, 256, 0, stream>>>(x, ln1_g, ln1_b, bufH);
    gemm_bt<0, 4><<<dim3(24, 32), 256, 0, stream>>>(bufH, W0, qkv_b, nullptr, bufA, 4096, 3072, 1024);
    attn2<<<1024, 256, 0, stream>>>(bufA, maskp, flag, bufO);
    gemm_bt<2, 2><<<dim3(16, 32), 256, 0, stream>>>(bufO, W1, proj_b, x, bufX1, 4096, 1024, 1024);
    ln_bf16<<<4096, 256, 0, stream>>>(bufX1, ln2_g, ln2_b, bufH);
    gemm_bt<1, 4><<<dim3(32, 32), 256, 0, stream>>>(bufH, W2, fc1_b, nullptr, bufA, 4096, 4096, 1024);
    gemm_bt<2, 2><<<dim3(16, 32), 256, 0, stream>>>(bufA, W3, fc2_b, bufX1, out, 4096, 1024, 4096);
  } else {
    unsigned short* bufW = (unsigned short*)wbase;               // shared 8.4 MB
    ln_bf16<<<4096, 256, 0, stream>>>(x, ln1_g, ln1_b, bufH);
    f32_to_bf16<<<2048, 256, 0, stream>>>(qkv_w, bufW, 3072 * 1024);
    gemm_bt<0, 4><<<dim3(24, 32), 256, 0, stream>>>(bufH, bufW, qkv_b, nullptr, bufA, 4096, 3072, 1024);
    attn2<<<1024, 256, 0, stream>>>(bufA, maskp, flag, bufO);
    f32_to_bf16<<<2048, 256, 0, stream>>>(proj_w, bufW, 1024 * 1024);
    gemm_bt<2, 2><<<dim3(16, 32), 256, 0, stream>>>(bufO, bufW, proj_b, x, bufX1, 4096, 1024, 1024);
    ln_bf16<<<4096, 256, 0, stream>>>(bufX1, ln2_g, ln2_b, bufH);
    f32_to_bf16<<<2048, 256, 0, stream>>>(fc1_w, bufW, 4096 * 1024);
    gemm_bt<1, 4><<<dim3(32, 32), 256, 0, stream>>>(bufH, bufW, fc1_b, nullptr, bufA, 4096, 4096, 1024);
    f32_to_bf16<<<2048, 256, 0, stream>>>(fc2_w, bufW, 1024 * 4096);
    gemm_bt<2, 2><<<dim3(16, 32), 256, 0, stream>>>(bufA, bufW, fc2_b, bufX1, out, 4096, 1024, 4096);
  }
}

// Round 4
// 409.624 us; speedup vs baseline: 1.1725x; 1.0099x over previous
//
#include <hip/hip_runtime.h>
#include <hip/hip_bf16.h>
#include <cstdint>
#include <cstddef>

// ---------------- types & helpers ----------------
typedef __attribute__((ext_vector_type(4))) float f32x4;
typedef __attribute__((ext_vector_type(8))) short s16x8;       // 8 bf16 (4 VGPRs) MFMA frag
typedef __attribute__((ext_vector_type(4))) unsigned int u32x4;
typedef __attribute__((ext_vector_type(4))) unsigned short u16x4;

__device__ __forceinline__ unsigned short f2bf(float f) {
  union { float f; unsigned int u; } v; v.f = f;
  return (unsigned short)((v.u + 0x7fffu + ((v.u >> 16) & 1u)) >> 16);  // RNE
}

__device__ __forceinline__ void gll16(const void* g, void* l) {
  // async global->LDS, 16B per lane. LDS dest must be wave-uniform base + lane*16.
  __builtin_amdgcn_global_load_lds(
      (const __attribute__((address_space(1))) void*)g,
      (__attribute__((address_space(3))) void*)l, 16, 0, 0);
}

// bijective XCD-chunk swizzle (guide m204): contiguous grid chunks per XCD
__device__ __forceinline__ int xcd_swz(int id, int nwg) {
  const int q = nwg >> 3, r = nwg & 7;
  const int xcd = id & 7, i = id >> 3;
  return ((xcd < r) ? xcd * (q + 1) : r * (q + 1) + (xcd - r) * q) + i;
}

// ---------------- mask dtype detector ----------------
__global__ void mask_detect(const unsigned char* __restrict__ m, int* __restrict__ flag) {
  __shared__ int f;
  if (threadIdx.x == 0) f = 0;
  __syncthreads();
  unsigned int found = 0;
  for (int i = threadIdx.x * 16; i < 65536; i += 256 * 16) {
    u32x4 v = *(const u32x4*)(m + i);
    found |= (v.x & 0xFFFFFF00u) | (v.y & 0xFFFFFF00u) |
             (v.z & 0xFFFFFF00u) | (v.w & 0xFFFFFF00u);
  }
  if (found) atomicOr(&f, 1);
  __syncthreads();
  if (threadIdx.x == 0) *flag = f;
}

// ---------------- LayerNorm (fp32 in -> bf16 out), one row per block ----------------
__global__ __launch_bounds__(256)
void ln_bf16(const float* __restrict__ x, const float* __restrict__ g,
             const float* __restrict__ bta, unsigned short* __restrict__ out) {
  const int row = blockIdx.x;
  const int t = threadIdx.x;
  const float* xr = x + (size_t)row * 1024;
  f32x4 v = *(const f32x4*)(xr + t * 4);
  float s  = v.x + v.y + v.z + v.w;
  float sq = v.x * v.x + v.y * v.y + v.z * v.z + v.w * v.w;
#pragma unroll
  for (int d = 1; d < 64; d <<= 1) { s += __shfl_xor(s, d, 64); sq += __shfl_xor(sq, d, 64); }
  __shared__ float ss[4], ssq[4];
  const int w = t >> 6;
  if ((t & 63) == 0) { ss[w] = s; ssq[w] = sq; }
  __syncthreads();
  s  = ss[0] + ss[1] + ss[2] + ss[3];
  sq = ssq[0] + ssq[1] + ssq[2] + ssq[3];
  const float mu  = s * (1.0f / 1024.0f);
  const float var = sq * (1.0f / 1024.0f) - mu * mu;
  const float rs  = rsqrtf(var + 1e-5f);
  f32x4 gv = *(const f32x4*)(g + t * 4);
  f32x4 bv = *(const f32x4*)(bta + t * 4);
  u16x4 o;
  o.x = f2bf((v.x - mu) * rs * gv.x + bv.x);
  o.y = f2bf((v.y - mu) * rs * gv.y + bv.y);
  o.z = f2bf((v.z - mu) * rs * gv.z + bv.z);
  o.w = f2bf((v.w - mu) * rs * gv.w + bv.w);
  *(u16x4*)(out + (size_t)row * 1024 + t * 4) = o;
}

// ---------------- fp32 -> bf16 convert (fallback path) ----------------
__global__ __launch_bounds__(256)
void f32_to_bf16(const float* __restrict__ in, unsigned short* __restrict__ out, int n) {
  for (int i = (blockIdx.x * 256 + threadIdx.x) * 4; i < n; i += gridDim.x * 256 * 4) {
    f32x4 v = *(const f32x4*)(in + i);
    u16x4 o = { f2bf(v.x), f2bf(v.y), f2bf(v.z), f2bf(v.w) };
    *(u16x4*)(out + i) = o;
  }
}

// ---------------- merged weight convert (all 4 weights, one launch) ----------------
__global__ __launch_bounds__(256)
void convert_weights(const float* __restrict__ w0, const float* __restrict__ w1,
                     const float* __restrict__ w2, const float* __restrict__ w3,
                     unsigned short* __restrict__ o0, unsigned short* __restrict__ o1,
                     unsigned short* __restrict__ o2, unsigned short* __restrict__ o3) {
  const int gid = blockIdx.x * 256 + threadIdx.x;
  for (int i = gid * 4; i < 12582912; i += gridDim.x * 256 * 4) {
    const float* src; unsigned short* dst; int off;
    if (i < 3145728)      { src = w0; dst = o0; off = i; }
    else if (i < 4194304) { src = w1; dst = o1; off = i - 3145728; }
    else if (i < 8388608) { src = w2; dst = o2; off = i - 4194304; }
    else                  { src = w3; dst = o3; off = i - 8388608; }
    f32x4 v = *(const f32x4*)(src + off);
    u16x4 o = { f2bf(v.x), f2bf(v.y), f2bf(v.z), f2bf(v.w) };
    *(u16x4*)(dst + off) = o;
  }
}

// ---------------- 256x256 8-wave phased BT-GEMM (QKV / FC1) ----------------
// C[M,N] = A[M,K] @ B[N,K]^T + bias. EPI 0: bf16 store. EPI 1: fast GELU -> bf16.
// 512 threads = 8 waves (2Mx4N), per-wave 128x64 out (8x4 frags). BK=64.
// 4 phases/K-tile (one C-quadrant x K=64 each), XOR-swizzled LDS, dbuf, setprio.
template<int EPI>
__global__ __launch_bounds__(512, 1)
void gemm256(const unsigned short* __restrict__ A, const unsigned short* __restrict__ Bw,
             const float* __restrict__ bias, void* __restrict__ Cout,
             int M, int N, int K, int nbx) {
  __shared__ unsigned short As[2][256 * 64];   // 32KB per slot
  __shared__ unsigned short Bs[2][256 * 64];   // 32KB per slot -> 128KB total
  const int tid = threadIdx.x;
  const int swz = xcd_swz(blockIdx.x, gridDim.x);
  const int bx = swz % nbx, by = swz / nbx;

  const int w = tid >> 6, l = tid & 63;
  const int wr = w >> 2, wc = w & 3;
  const int lr = l & 15, lk = l >> 4;
  const int row0A = by * 256, row0B = bx * 256;

  f32x4 acc[8][4] = {};

  // staging: source chunk pre-swizzled (j0 ^ (row&7)), LDS dest linear (rule #21)
  auto stageA = [&](int slot, int kt) {
#pragma unroll
    for (int ra = 0; ra < 4; ++ra) {
      const int c = ra * 512 + tid;
      const int rr = c >> 3, j0 = c & 7;
      gll16(A + (size_t)(row0A + rr) * K + kt + (j0 ^ (rr & 7)) * 8, &As[slot][c * 8]);
    }
  };
  auto stageB = [&](int slot, int kt) {
#pragma unroll
    for (int ra = 0; ra < 4; ++ra) {
      const int c = ra * 512 + tid;
      const int rr = c >> 3, j0 = c & 7;
      gll16(Bw + (size_t)(row0B + rr) * K + kt + (j0 ^ (rr & 7)) * 8, &Bs[slot][c * 8]);
    }
  };
  auto rdA = [&](int slot, int m, int ks) -> s16x8 {
    const int row = wr * 128 + m * 16 + lr;
    const int byte = (row * 128 + ks * 64 + lk * 16) ^ ((row & 7) << 4);
    return *(const s16x8*)((const char*)&As[slot][0] + byte);
  };
  auto rdB = [&](int slot, int n, int ks) -> s16x8 {
    const int row = wc * 64 + n * 16 + lr;
    const int byte = (row * 128 + ks * 64 + lk * 16) ^ ((row & 7) << 4);
    return *(const s16x8*)((const char*)&Bs[slot][0] + byte);
  };

  stageA(0, 0); stageB(0, 0);
  asm volatile("s_waitcnt vmcnt(0)" ::: "memory");
  __syncthreads();

  const int nt = K >> 6;
  s16x8 af[4][2], b01[2][2], b23[2][2];
  for (int t = 0; t < nt; ++t) {
    const int cur = t & 1;
    const int ktn = (t + 1 < nt) ? (t + 1) * 64 : 0;   // tail: harmless re-stage of tile 0
    // ---- P0: quadrant (m0-3, n0-1); stage next A ----
#pragma unroll
    for (int m = 0; m < 4; ++m) { af[m][0] = rdA(cur, m, 0); af[m][1] = rdA(cur, m, 1); }
#pragma unroll
    for (int n = 0; n < 2; ++n) { b01[n][0] = rdB(cur, n, 0); b01[n][1] = rdB(cur, n, 1); }
    stageA(cur ^ 1, ktn);
    __builtin_amdgcn_s_setprio(1);
#pragma unroll
    for (int m = 0; m < 4; ++m)
#pragma unroll
      for (int n = 0; n < 2; ++n)
#pragma unroll
        for (int ks = 0; ks < 2; ++ks)
          acc[m][n] = __builtin_amdgcn_mfma_f32_16x16x32_bf16(af[m][ks], b01[n][ks], acc[m][n], 0, 0, 0);
    __builtin_amdgcn_s_setprio(0);
    __syncthreads();
    // ---- P1: quadrant (m0-3, n2-3); stage next B ----
#pragma unroll
    for (int n = 0; n < 2; ++n) { b23[n][0] = rdB(cur, n + 2, 0); b23[n][1] = rdB(cur, n + 2, 1); }
    stageB(cur ^ 1, ktn);
    __builtin_amdgcn_s_setprio(1);
#pragma unroll
    for (int m = 0; m < 4; ++m)
#pragma unroll
      for (int n = 0; n < 2; ++n)
#pragma unroll
        for (int ks = 0; ks < 2; ++ks)
          acc[m][n + 2] = __builtin_amdgcn_mfma_f32_16x16x32_bf16(af[m][ks], b23[n][ks], acc[m][n + 2], 0, 0, 0);
    __builtin_amdgcn_s_setprio(0);
    __syncthreads();
    // ---- P2: quadrant (m4-7, n2-3) ----
#pragma unroll
    for (int m = 0; m < 4; ++m) { af[m][0] = rdA(cur, m + 4, 0); af[m][1] = rdA(cur, m + 4, 1); }
    __builtin_amdgcn_s_setprio(1);
#pragma unroll
    for (int m = 0; m < 4; ++m)
#pragma unroll
      for (int n = 0; n < 2; ++n)
#pragma unroll
        for (int ks = 0; ks < 2; ++ks)
          acc[m + 4][n + 2] = __builtin_amdgcn_mfma_f32_16x16x32_bf16(af[m][ks], b23[n][ks], acc[m + 4][n + 2], 0, 0, 0);
    __builtin_amdgcn_s_setprio(0);
    __syncthreads();
    // ---- P3: quadrant (m4-7, n0-1); boundary wait ----
    __builtin_amdgcn_s_setprio(1);
#pragma unroll
    for (int m = 0; m < 4; ++m)
#pragma unroll
      for (int n = 0; n < 2; ++n)
#pragma unroll
        for (int ks = 0; ks < 2; ++ks)
          acc[m + 4][n] = __builtin_amdgcn_mfma_f32_16x16x32_bf16(af[m][ks], b01[n][ks], acc[m + 4][n], 0, 0, 0);
    __builtin_amdgcn_s_setprio(0);
    asm volatile("s_waitcnt vmcnt(0)" ::: "memory");   // next tile landed (issued at P0/P1)
    __syncthreads();
  }
  // epilogue
#pragma unroll
  for (int m = 0; m < 8; ++m) {
#pragma unroll
    for (int n = 0; n < 4; ++n) {
      const int col = bx * 256 + wc * 64 + n * 16 + lr;
      const float bval = bias[col];
#pragma unroll
      for (int r2 = 0; r2 < 4; ++r2) {
        const int row = by * 256 + wr * 128 + m * 16 + lk * 4 + r2;
        float vv = acc[m][n][r2] + bval;
        const size_t idx = (size_t)row * N + col;
        if (EPI == 0) {
          ((unsigned short*)Cout)[idx] = f2bf(vv);
        } else {
          const float t2 = vv * (1.5957691216f + 0.0713548163f * vv * vv);
          ((unsigned short*)Cout)[idx] = f2bf(vv / (1.0f + __expf(-t2)));
        }
      }
    }
  }
}

// ---------------- 128xBN dbuf BT-GEMM (proj / fc2), 1D grid + XCD swizzle ----------------
// EPI 2: + resid -> fp32 out.
template<int EPI, int NW>
__global__ __launch_bounds__(256)
void gemm_bt(const unsigned short* __restrict__ A, const unsigned short* __restrict__ Bw,
             const float* __restrict__ bias, const float* __restrict__ resid,
             void* __restrict__ Cout, int M, int N, int K, int nbx) {
  constexpr int BN = 32 * NW;
  __shared__ unsigned short As[2][128 * 64];
  __shared__ unsigned short Bs[2][BN * 64];
  const int tid = threadIdx.x;
  const int swz = xcd_swz(blockIdx.x, gridDim.x);
  const int bx = swz % nbx, by = swz / nbx;
  const int w = tid >> 6, l = tid & 63;
  const int wr = w >> 1, wc = w & 1;
  const int lr = l & 15, lk = l >> 4;

  f32x4 acc[4][NW] = {};
  const int row0A = by * 128, row0B = bx * BN;

  auto stage = [&](int buf, int kt) {
#pragma unroll
    for (int it = 0; it < 4; ++it) {
      const int c = it * 256 + tid;
      const int r = c >> 3, c8 = (c & 7) * 8;
      gll16(A + (size_t)(row0A + r) * K + kt + c8, &As[buf][c * 8]);
      if (it < NW)
        gll16(Bw + (size_t)(row0B + r) * K + kt + c8, &Bs[buf][c * 8]);
    }
  };

  stage(0, 0);
  asm volatile("s_waitcnt vmcnt(0)" ::: "memory");
  __syncthreads();

  const int nsteps = K >> 6;
  for (int t = 0; t < nsteps; ++t) {
    const int cur = t & 1;
    if (t + 1 < nsteps) stage(cur ^ 1, (t + 1) * 64);
    const unsigned short* Ac = As[cur];
    const unsigned short* Bc = Bs[cur];
#pragma unroll
    for (int ks = 0; ks < 2; ++ks) {
      s16x8 af[4], bfr[NW];
#pragma unroll
      for (int m = 0; m < 4; ++m)
        af[m] = *(const s16x8*)&Ac[(wr * 64 + m * 16 + lr) * 64 + ks * 32 + lk * 8];
#pragma unroll
      for (int n = 0; n < NW; ++n)
        bfr[n] = *(const s16x8*)&Bc[(wc * (BN / 2) + n * 16 + lr) * 64 + ks * 32 + lk * 8];
#pragma unroll
      for (int m = 0; m < 4; ++m)
#pragma unroll
        for (int n = 0; n < NW; ++n)
          acc[m][n] = __builtin_amdgcn_mfma_f32_16x16x32_bf16(af[m], bfr[n], acc[m][n], 0, 0, 0);
    }
    if (t + 1 < nsteps) {
      asm volatile("s_waitcnt vmcnt(0)" ::: "memory");
      __syncthreads();
    }
  }
#pragma unroll
  for (int m = 0; m < 4; ++m) {
#pragma unroll
    for (int n = 0; n < NW; ++n) {
      const int col = bx * BN + wc * (BN / 2) + n * 16 + lr;
      const float bval = bias[col];
#pragma unroll
      for (int r2 = 0; r2 < 4; ++r2) {
        const int row = by * 128 + wr * 64 + m * 16 + lk * 4 + r2;
        float vv = acc[m][n][r2] + bval;
        const size_t idx = (size_t)row * N + col;
        if (EPI == 0) {
          ((unsigned short*)Cout)[idx] = f2bf(vv);
        } else if (EPI == 1) {
          const float t2 = vv * (1.5957691216f + 0.0713548163f * vv * vv);
          ((unsigned short*)Cout)[idx] = f2bf(vv / (1.0f + __expf(-t2)));
        } else {
          ((float*)Cout)[idx] = vv + resid[idx];
        }
      }
    }
  }
}

// ---------------- flash attention v2: swapped QK^T, swizzled LDS, softmax1 ----------------
__global__ __launch_bounds__(256, 4)
void attn2(const unsigned short* __restrict__ qkv, const void* __restrict__ maskp,
           const int* __restrict__ flag, unsigned short* __restrict__ o_ws) {
  __shared__ unsigned short Qs[64 * 64];
  __shared__ unsigned short Ks[64 * 64];
  __shared__ unsigned short Vts[64 * 64];
  __shared__ unsigned short Ps[4][16 * 64];

  const int tid = threadIdx.x;
  const int orig = blockIdx.x;
  const int swzb = (orig & 7) * 128 + (orig >> 3);
  const int bh = swzb >> 4, qt = swzb & 15;
  const int b = bh >> 4, h = bh & 15;
  const int q0 = qt * 64;
  const int w = tid >> 6, l = tid & 63;
  const int lr = l & 15, lk = l >> 4;
  const size_t rowbase = (size_t)b * 1024;
  const int qoff = h * 64, koff = 1024 + h * 64, voff = 2048 + h * 64;

#pragma unroll
  for (int it = 0; it < 2; ++it) {
    const int c = it * 256 + tid;
    const int r = c >> 3, j0 = c & 7;
    const int jsrc = j0 ^ (r & 7);
    gll16(qkv + (rowbase + q0 + r) * 3072 + qoff + jsrc * 8, Qs + c * 8);
  }
  const int mask_is_byte = *flag;
  const int qrow_g = q0 + w * 16 + lr;
  const unsigned char* mrow_b = (const unsigned char*)maskp + ((size_t)b * 1024 + qrow_g) * 1024;
  const int* mrow_i = (const int*)maskp + ((size_t)b * 1024 + qrow_g) * 1024;

  const int np = tid & 31, dg = tid >> 5;

  float m_r = 0.f, l_r = 1.f;
  f32x4 acc_o[4] = {};

  for (int nt = 0; nt < 16; ++nt) {
    const int n0 = nt * 64;
    const unsigned short* vsrc = qkv + (rowbase + n0 + 2 * np) * 3072 + voff + dg * 8;
    u32x4 va = *(const u32x4*)vsrc;
    u32x4 vb = *(const u32x4*)(vsrc + 3072);
    unsigned int mb[4];
    if (mask_is_byte) {
#pragma unroll
      for (int n = 0; n < 4; ++n)
        mb[n] = *(const unsigned int*)(mrow_b + n0 + n * 16 + lk * 4);
    } else {
#pragma unroll
      for (int n = 0; n < 4; ++n) {
        u32x4 t4 = *(const u32x4*)(mrow_i + n0 + n * 16 + lk * 4);
        mb[n] = (t4.x ? 1u : 0u) | (t4.y ? 0x100u : 0u) |
                (t4.z ? 0x10000u : 0u) | (t4.w ? 0x1000000u : 0u);
      }
    }
    __syncthreads();
#pragma unroll
    for (int it = 0; it < 2; ++it) {
      const int c = it * 256 + tid;
      const int r = c >> 3, j0 = c & 7;
      const int jsrc = j0 ^ (r & 7);
      gll16(qkv + (rowbase + n0 + r) * 3072 + koff + jsrc * 8, Ks + c * 8);
    }
    {
      const unsigned short* ea = (const unsigned short*)&va;
      const unsigned short* eb = (const unsigned short*)&vb;
#pragma unroll
      for (int j = 0; j < 8; ++j) {
        const int d = dg * 8 + j;
        const unsigned int pv = (unsigned int)ea[j] | ((unsigned int)eb[j] << 16);
        const int byte = (d * 128 + np * 4) ^ ((d & 7) << 4);
        *(unsigned int*)((char*)Vts + byte) = pv;
      }
    }
    asm volatile("s_waitcnt vmcnt(0)" ::: "memory");
    __syncthreads();

    f32x4 s_acc[4] = {};
#pragma unroll
    for (int ks = 0; ks < 2; ++ks) {
      const int cb = ks * 64 + lk * 16;
      const s16x8 qf = *(const s16x8*)((char*)Qs + (((w * 16 + lr) * 128 + cb) ^ ((lr & 7) << 4)));
#pragma unroll
      for (int n = 0; n < 4; ++n) {
        const s16x8 kf = *(const s16x8*)((char*)Ks + (((n * 16 + lr) * 128 + cb) ^ ((lr & 7) << 4)));
        s_acc[n] = __builtin_amdgcn_mfma_f32_16x16x32_bf16(kf, qf, s_acc[n], 0, 0, 0);
      }
    }
    float pmax = -3.0e38f;
#pragma unroll
    for (int n = 0; n < 4; ++n)
#pragma unroll
      for (int r2 = 0; r2 < 4; ++r2) {
        float s = s_acc[n][r2] * 0.125f;
        if ((mb[n] >> (8 * r2)) & 0xff) s = -3.0e38f;
        s_acc[n][r2] = s;
        pmax = fmaxf(pmax, s);
      }
    pmax = fmaxf(pmax, __shfl_xor(pmax, 16, 64));
    pmax = fmaxf(pmax, __shfl_xor(pmax, 32, 64));
    const float mnew = fmaxf(m_r, pmax);
    const float resc = __expf(m_r - mnew);
    m_r = mnew;
    float psum = 0.f;
    unsigned int pk[4][2];
#pragma unroll
    for (int n = 0; n < 4; ++n)
#pragma unroll
      for (int h2 = 0; h2 < 2; ++h2) {
        const float p0 = __expf(s_acc[n][2 * h2]     - mnew);
        const float p1 = __expf(s_acc[n][2 * h2 + 1] - mnew);
        psum += p0 + p1;
        pk[n][h2] = (unsigned int)f2bf(p0) | ((unsigned int)f2bf(p1) << 16);
      }
    psum += __shfl_xor(psum, 16, 64);
    psum += __shfl_xor(psum, 32, 64);
    l_r = l_r * resc + psum;
    char* psw = (char*)&Ps[w][0];
#pragma unroll
    for (int n = 0; n < 4; ++n)
#pragma unroll
      for (int h2 = 0; h2 < 2; ++h2) {
        const int byte = (lr * 128 + n * 32 + lk * 8 + h2 * 4) ^ ((lr & 7) << 4);
        *(unsigned int*)(psw + byte) = pk[n][h2];
      }
    float rs4[4];
#pragma unroll
    for (int r2 = 0; r2 < 4; ++r2)
      rs4[r2] = __shfl(resc, (l & 48) | (lk * 4 + r2), 64);
#pragma unroll
    for (int dn = 0; dn < 4; ++dn)
#pragma unroll
      for (int r2 = 0; r2 < 4; ++r2) acc_o[dn][r2] *= rs4[r2];
#pragma unroll
    for (int ks = 0; ks < 2; ++ks) {
      const int cb = ks * 64 + lk * 16;
      const s16x8 ap = *(const s16x8*)(psw + ((lr * 128 + cb) ^ ((lr & 7) << 4)));
#pragma unroll
      for (int dn = 0; dn < 4; ++dn) {
        const s16x8 bv = *(const s16x8*)((char*)Vts + (((dn * 16 + lr) * 128 + cb) ^ ((lr & 7) << 4)));
        acc_o[dn] = __builtin_amdgcn_mfma_f32_16x16x32_bf16(ap, bv, acc_o[dn], 0, 0, 0);
      }
    }
  }
  const float linv = 1.0f / l_r;
  float li4[4];
#pragma unroll
  for (int r2 = 0; r2 < 4; ++r2)
    li4[r2] = __shfl(linv, (l & 48) | (lk * 4 + r2), 64);
#pragma unroll
  for (int dn = 0; dn < 4; ++dn)
#pragma unroll
    for (int r2 = 0; r2 < 4; ++r2) {
      const int qrow = q0 + w * 16 + lk * 4 + r2;
      const int dcol = h * 64 + dn * 16 + lr;
      o_ws[(rowbase + qrow) * 1024 + dcol] = f2bf(acc_o[dn][r2] * li4[r2]);
    }
}

// ---------------- launch ----------------
extern "C" void kernel_launch(void* const* d_in, const int* in_sizes, int n_in,
                              void* d_out, int out_size, void* d_ws, size_t ws_size,
                              hipStream_t stream) {
  const float* x      = (const float*)d_in[0];
  const void*  maskp  = d_in[1];
  const float* ln1_g  = (const float*)d_in[2];
  const float* ln1_b  = (const float*)d_in[3];
  const float* qkv_w  = (const float*)d_in[4];
  const float* qkv_b  = (const float*)d_in[5];
  const float* proj_w = (const float*)d_in[6];
  const float* proj_b = (const float*)d_in[7];
  const float* ln2_g  = (const float*)d_in[8];
  const float* ln2_b  = (const float*)d_in[9];
  const float* fc1_w  = (const float*)d_in[10];
  const float* fc1_b  = (const float*)d_in[11];
  const float* fc2_w  = (const float*)d_in[12];
  const float* fc2_b  = (const float*)d_in[13];
  float* out = (float*)d_out;

  char* ws = (char*)d_ws;
  int* flag            = (int*)ws;                                   // 256 B
  unsigned short* bufA = (unsigned short*)(ws + 256);                // 33.6 MB
  unsigned short* bufH = (unsigned short*)(ws + 256 + 33554432);     // 8.4 MB
  unsigned short* bufO = (unsigned short*)(ws + 256 + 33554432 + 8388608);          // 8.4 MB
  float* bufX1         = (float*)(ws + 256 + 33554432 + 2 * 8388608);               // 16.8 MB
  char* wbase          = ws + 256 + 33554432 + 2 * 8388608 + 16777216;

  mask_detect<<<1, 256, 0, stream>>>((const unsigned char*)maskp, flag);

  const bool bigws = ws_size >= (size_t)92274944;
  if (bigws) {
    unsigned short* W0 = (unsigned short*)wbase;                 // qkv  6.3 MB
    unsigned short* W1 = (unsigned short*)(wbase + 6291456);     // proj 2.1 MB
    unsigned short* W2 = (unsigned short*)(wbase + 8388608);     // fc1  8.4 MB
    unsigned short* W3 = (unsigned short*)(wbase + 16777216);    // fc2  8.4 MB
    convert_weights<<<4096, 256, 0, stream>>>(qkv_w, proj_w, fc1_w, fc2_w, W0, W1, W2, W3);
    ln_bf16<<<4096, 256, 0, stream>>>(x, ln1_g, ln1_b, bufH);
    gemm256<0><<<192, 512, 0, stream>>>(bufH, W0, qkv_b, bufA, 4096, 3072, 1024, 12);
    attn2<<<1024, 256, 0, stream>>>(bufA, maskp, flag, bufO);
    gemm_bt<2, 4><<<256, 256, 0, stream>>>(bufO, W1, proj_b, x, bufX1, 4096, 1024, 1024, 8);
    ln_bf16<<<4096, 256, 0, stream>>>(bufX1, ln2_g, ln2_b, bufH);
    gemm256<1><<<256, 512, 0, stream>>>(bufH, W2, fc1_b, bufA, 4096, 4096, 1024, 16);
    gemm_bt<2, 4><<<256, 256, 0, stream>>>(bufA, W3, fc2_b, bufX1, out, 4096, 1024, 4096, 8);
  } else {
    unsigned short* bufW = (unsigned short*)wbase;               // shared 8.4 MB
    ln_bf16<<<4096, 256, 0, stream>>>(x, ln1_g, ln1_b, bufH);
    f32_to_bf16<<<2048, 256, 0, stream>>>(qkv_w, bufW, 3072 * 1024);
    gemm256<0><<<192, 512, 0, stream>>>(bufH, bufW, qkv_b, bufA, 4096, 3072, 1024, 12);
    attn2<<<1024, 256, 0, stream>>>(bufA, maskp, flag, bufO);
    f32_to_bf16<<<2048, 256, 0, stream>>>(proj_w, bufW, 1024 * 1024);
    gemm_bt<2, 4><<<256, 256, 0, stream>>>(bufO, bufW, proj_b, x, bufX1, 4096, 1024, 1024, 8);
    ln_bf16<<<4096, 256, 0, stream>>>(bufX1, ln2_g, ln2_b, bufH);
    f32_to_bf16<<<2048, 256, 0, stream>>>(fc1_w, bufW, 4096 * 1024);
    gemm256<1><<<256, 512, 0, stream>>>(bufH, bufW, fc1_b, bufA, 4096, 4096, 1024, 16);
    f32_to_bf16<<<2048, 256, 0, stream>>>(fc2_w, bufW, 1024 * 4096);
    gemm_bt<2, 4><<<256, 256, 0, stream>>>(bufA, bufW, fc2_b, bufX1, out, 4096, 1024, 4096, 8);
  }
}

// Round 6
// 408.381 us; speedup vs baseline: 1.1761x; 1.0030x over previous
//
#include <hip/hip_runtime.h>
#include <hip/hip_bf16.h>
#include <cstdint>
#include <cstddef>

// ---------------- types & helpers ----------------
typedef __attribute__((ext_vector_type(4))) float f32x4;
typedef __attribute__((ext_vector_type(8))) short s16x8;       // 8 bf16 (4 VGPRs) MFMA frag
typedef __attribute__((ext_vector_type(4))) unsigned int u32x4;
typedef __attribute__((ext_vector_type(4))) unsigned short u16x4;

__device__ __forceinline__ unsigned short f2bf(float f) {
  union { float f; unsigned int u; } v; v.f = f;
  return (unsigned short)((v.u + 0x7fffu + ((v.u >> 16) & 1u)) >> 16);  // RNE
}

__device__ __forceinline__ void gll16(const void* g, void* l) {
  // async global->LDS, 16B per lane. LDS dest must be wave-uniform base + lane*16.
  __builtin_amdgcn_global_load_lds(
      (const __attribute__((address_space(1))) void*)g,
      (__attribute__((address_space(3))) void*)l, 16, 0, 0);
}

// bijective XCD-chunk swizzle (guide m204)
__device__ __forceinline__ int xcd_swz(int id, int nwg) {
  const int q = nwg >> 3, r = nwg & 7;
  const int xcd = id & 7, i = id >> 3;
  return ((xcd < r) ? xcd * (q + 1) : r * (q + 1) + (xcd - r) * q) + i;
}

// ---------------- mask dtype detector (fallback path only) ----------------
__global__ void mask_detect(const unsigned char* __restrict__ m, int* __restrict__ flag) {
  __shared__ int f;
  if (threadIdx.x == 0) f = 0;
  __syncthreads();
  unsigned int found = 0;
  for (int i = threadIdx.x * 16; i < 65536; i += 256 * 16) {
    u32x4 v = *(const u32x4*)(m + i);
    found |= (v.x & 0xFFFFFF00u) | (v.y & 0xFFFFFF00u) |
             (v.z & 0xFFFFFF00u) | (v.w & 0xFFFFFF00u);
  }
  if (found) atomicOr(&f, 1);
  __syncthreads();
  if (threadIdx.x == 0) *flag = f;
}

// ---------------- LayerNorm (fp32 in -> bf16 out), one row per block ----------------
__global__ __launch_bounds__(256)
void ln_bf16(const float* __restrict__ x, const float* __restrict__ g,
             const float* __restrict__ bta, unsigned short* __restrict__ out) {
  const int row = blockIdx.x;
  const int t = threadIdx.x;
  const float* xr = x + (size_t)row * 1024;
  f32x4 v = *(const f32x4*)(xr + t * 4);
  float s  = v.x + v.y + v.z + v.w;
  float sq = v.x * v.x + v.y * v.y + v.z * v.z + v.w * v.w;
#pragma unroll
  for (int d = 1; d < 64; d <<= 1) { s += __shfl_xor(s, d, 64); sq += __shfl_xor(sq, d, 64); }
  __shared__ float ss[4], ssq[4];
  const int w = t >> 6;
  if ((t & 63) == 0) { ss[w] = s; ssq[w] = sq; }
  __syncthreads();
  s  = ss[0] + ss[1] + ss[2] + ss[3];
  sq = ssq[0] + ssq[1] + ssq[2] + ssq[3];
  const float mu  = s * (1.0f / 1024.0f);
  const float var = sq * (1.0f / 1024.0f) - mu * mu;
  const float rs  = rsqrtf(var + 1e-5f);
  f32x4 gv = *(const f32x4*)(g + t * 4);
  f32x4 bv = *(const f32x4*)(bta + t * 4);
  u16x4 o;
  o.x = f2bf((v.x - mu) * rs * gv.x + bv.x);
  o.y = f2bf((v.y - mu) * rs * gv.y + bv.y);
  o.z = f2bf((v.z - mu) * rs * gv.z + bv.z);
  o.w = f2bf((v.w - mu) * rs * gv.w + bv.w);
  *(u16x4*)(out + (size_t)row * 1024 + t * 4) = o;
}

// ---------------- fp32 -> bf16 convert (fallback path) ----------------
__global__ __launch_bounds__(256)
void f32_to_bf16(const float* __restrict__ in, unsigned short* __restrict__ out, int n) {
  for (int i = (blockIdx.x * 256 + threadIdx.x) * 4; i < n; i += gridDim.x * 256 * 4) {
    f32x4 v = *(const f32x4*)(in + i);
    u16x4 o = { f2bf(v.x), f2bf(v.y), f2bf(v.z), f2bf(v.w) };
    *(u16x4*)(out + i) = o;
  }
}

// ---------------- merged weight convert + mask detect (one launch) ----------------
__global__ __launch_bounds__(256)
void convert_weights(const float* __restrict__ w0, const float* __restrict__ w1,
                     const float* __restrict__ w2, const float* __restrict__ w3,
                     unsigned short* __restrict__ o0, unsigned short* __restrict__ o1,
                     unsigned short* __restrict__ o2, unsigned short* __restrict__ o3,
                     const unsigned char* __restrict__ maskp, int* __restrict__ flag) {
  if (blockIdx.x == 0) {
    __shared__ int f;
    if (threadIdx.x == 0) f = 0;
    __syncthreads();
    unsigned int found = 0;
    for (int i = threadIdx.x * 16; i < 65536; i += 256 * 16) {
      u32x4 v = *(const u32x4*)(maskp + i);
      found |= (v.x & 0xFFFFFF00u) | (v.y & 0xFFFFFF00u) |
               (v.z & 0xFFFFFF00u) | (v.w & 0xFFFFFF00u);
    }
    if (found) atomicOr(&f, 1);
    __syncthreads();
    if (threadIdx.x == 0) *flag = f;
  }
  const int gid = blockIdx.x * 256 + threadIdx.x;
  for (int i = gid * 4; i < 12582912; i += gridDim.x * 256 * 4) {
    const float* src; unsigned short* dst; int off;
    if (i < 3145728)      { src = w0; dst = o0; off = i; }
    else if (i < 4194304) { src = w1; dst = o1; off = i - 3145728; }
    else if (i < 8388608) { src = w2; dst = o2; off = i - 4194304; }
    else                  { src = w3; dst = o3; off = i - 8388608; }
    f32x4 v = *(const f32x4*)(src + off);
    u16x4 o = { f2bf(v.x), f2bf(v.y), f2bf(v.z), f2bf(v.w) };
    *(u16x4*)(dst + off) = o;
  }
}

// ---------------- 256x256 8-wave phased BT-GEMM (QKV / FC1) ----------------
template<int EPI>
__global__ __launch_bounds__(512, 1)
void gemm256(const unsigned short* __restrict__ A, const unsigned short* __restrict__ Bw,
             const float* __restrict__ bias, void* __restrict__ Cout,
             int M, int N, int K, int nbx) {
  __shared__ unsigned short As[2][256 * 64];
  __shared__ unsigned short Bs[2][256 * 64];
  const int tid = threadIdx.x;
  const int swz = xcd_swz(blockIdx.x, gridDim.x);
  const int bx = swz % nbx, by = swz / nbx;

  const int w = tid >> 6, l = tid & 63;
  const int wr = w >> 2, wc = w & 3;
  const int lr = l & 15, lk = l >> 4;
  const int row0A = by * 256, row0B = bx * 256;

  f32x4 acc[8][4] = {};

  auto stageA = [&](int slot, int kt) {
#pragma unroll
    for (int ra = 0; ra < 4; ++ra) {
      const int c = ra * 512 + tid;
      const int rr = c >> 3, j0 = c & 7;
      gll16(A + (size_t)(row0A + rr) * K + kt + (j0 ^ (rr & 7)) * 8, &As[slot][c * 8]);
    }
  };
  auto stageB = [&](int slot, int kt) {
#pragma unroll
    for (int ra = 0; ra < 4; ++ra) {
      const int c = ra * 512 + tid;
      const int rr = c >> 3, j0 = c & 7;
      gll16(Bw + (size_t)(row0B + rr) * K + kt + (j0 ^ (rr & 7)) * 8, &Bs[slot][c * 8]);
    }
  };
  auto rdA = [&](int slot, int m, int ks) -> s16x8 {
    const int row = wr * 128 + m * 16 + lr;
    const int byte = (row * 128 + ks * 64 + lk * 16) ^ ((row & 7) << 4);
    return *(const s16x8*)((const char*)&As[slot][0] + byte);
  };
  auto rdB = [&](int slot, int n, int ks) -> s16x8 {
    const int row = wc * 64 + n * 16 + lr;
    const int byte = (row * 128 + ks * 64 + lk * 16) ^ ((row & 7) << 4);
    return *(const s16x8*)((const char*)&Bs[slot][0] + byte);
  };

  stageA(0, 0); stageB(0, 0);
  asm volatile("s_waitcnt vmcnt(0)" ::: "memory");
  __syncthreads();

  const int nt = K >> 6;
  s16x8 af[4][2], b01[2][2], b23[2][2];
  for (int t = 0; t < nt; ++t) {
    const int cur = t & 1;
    const int ktn = (t + 1 < nt) ? (t + 1) * 64 : 0;
    // ---- P0: quadrant (m0-3, n0-1); stage next A ----
#pragma unroll
    for (int m = 0; m < 4; ++m) { af[m][0] = rdA(cur, m, 0); af[m][1] = rdA(cur, m, 1); }
#pragma unroll
    for (int n = 0; n < 2; ++n) { b01[n][0] = rdB(cur, n, 0); b01[n][1] = rdB(cur, n, 1); }
    stageA(cur ^ 1, ktn);
    __builtin_amdgcn_s_setprio(1);
#pragma unroll
    for (int m = 0; m < 4; ++m)
#pragma unroll
      for (int n = 0; n < 2; ++n)
#pragma unroll
        for (int ks = 0; ks < 2; ++ks)
          acc[m][n] = __builtin_amdgcn_mfma_f32_16x16x32_bf16(af[m][ks], b01[n][ks], acc[m][n], 0, 0, 0);
    __builtin_amdgcn_s_setprio(0);
    __syncthreads();
    // ---- P1: quadrant (m0-3, n2-3); stage next B ----
#pragma unroll
    for (int n = 0; n < 2; ++n) { b23[n][0] = rdB(cur, n + 2, 0); b23[n][1] = rdB(cur, n + 2, 1); }
    stageB(cur ^ 1, ktn);
    __builtin_amdgcn_s_setprio(1);
#pragma unroll
    for (int m = 0; m < 4; ++m)
#pragma unroll
      for (int n = 0; n < 2; ++n)
#pragma unroll
        for (int ks = 0; ks < 2; ++ks)
          acc[m][n + 2] = __builtin_amdgcn_mfma_f32_16x16x32_bf16(af[m][ks], b23[n][ks], acc[m][n + 2], 0, 0, 0);
    __builtin_amdgcn_s_setprio(0);
    __syncthreads();
    // ---- P2: quadrant (m4-7, n2-3) ----
#pragma unroll
    for (int m = 0; m < 4; ++m) { af[m][0] = rdA(cur, m + 4, 0); af[m][1] = rdA(cur, m + 4, 1); }
    __builtin_amdgcn_s_setprio(1);
#pragma unroll
    for (int m = 0; m < 4; ++m)
#pragma unroll
      for (int n = 0; n < 2; ++n)
#pragma unroll
        for (int ks = 0; ks < 2; ++ks)
          acc[m + 4][n + 2] = __builtin_amdgcn_mfma_f32_16x16x32_bf16(af[m][ks], b23[n][ks], acc[m + 4][n + 2], 0, 0, 0);
    __builtin_amdgcn_s_setprio(0);
    __syncthreads();
    // ---- P3: quadrant (m4-7, n0-1); boundary wait ----
    __builtin_amdgcn_s_setprio(1);
#pragma unroll
    for (int m = 0; m < 4; ++m)
#pragma unroll
      for (int n = 0; n < 2; ++n)
#pragma unroll
        for (int ks = 0; ks < 2; ++ks)
          acc[m + 4][n] = __builtin_amdgcn_mfma_f32_16x16x32_bf16(af[m][ks], b01[n][ks], acc[m + 4][n], 0, 0, 0);
    __builtin_amdgcn_s_setprio(0);
    asm volatile("s_waitcnt vmcnt(0)" ::: "memory");
    __syncthreads();
  }
  // epilogue
#pragma unroll
  for (int m = 0; m < 8; ++m) {
#pragma unroll
    for (int n = 0; n < 4; ++n) {
      const int col = bx * 256 + wc * 64 + n * 16 + lr;
      const float bval = bias[col];
#pragma unroll
      for (int r2 = 0; r2 < 4; ++r2) {
        const int row = by * 256 + wr * 128 + m * 16 + lk * 4 + r2;
        float vv = acc[m][n][r2] + bval;
        const size_t idx = (size_t)row * N + col;
        if (EPI == 0) {
          ((unsigned short*)Cout)[idx] = f2bf(vv);
        } else {
          const float t2 = vv * (1.5957691216f + 0.0713548163f * vv * vv);
          ((unsigned short*)Cout)[idx] = f2bf(vv / (1.0f + __expf(-t2)));
        }
      }
    }
  }
}

// ---------------- 128x128 triple-buffered counted-vmcnt BT-GEMM (proj / fc2) ----------------
// T4: stage 2 K-tiles ahead, wait vmcnt(8) per step (8 = per-thread loads of one tile),
// never drain to 0 in the main loop. 96 KB LDS, 256 thr, EPI 2: + resid -> fp32.
template<int EPI, int NW>
__global__ __launch_bounds__(256)
void gemm_bt(const unsigned short* __restrict__ A, const unsigned short* __restrict__ Bw,
             const float* __restrict__ bias, const float* __restrict__ resid,
             void* __restrict__ Cout, int M, int N, int K, int nbx) {
  constexpr int BN = 32 * NW;
  static_assert(NW == 4, "vmcnt literal assumes 8 loads/tile/thread");
  __shared__ unsigned short As[3][128 * 64];
  __shared__ unsigned short Bs[3][BN * 64];
  const int tid = threadIdx.x;
  const int swz = xcd_swz(blockIdx.x, gridDim.x);
  const int bx = swz % nbx, by = swz / nbx;
  const int w = tid >> 6, l = tid & 63;
  const int wr = w >> 1, wc = w & 1;
  const int lr = l & 15, lk = l >> 4;

  f32x4 acc[4][NW] = {};
  const int row0A = by * 128, row0B = bx * BN;

  auto stage = [&](int buf, int kt) {
#pragma unroll
    for (int it = 0; it < 4; ++it) {
      const int c = it * 256 + tid;
      const int r = c >> 3, c8 = (c & 7) * 8;
      gll16(A + (size_t)(row0A + r) * K + kt + c8, &As[buf][c * 8]);
      gll16(Bw + (size_t)(row0B + r) * K + kt + c8, &Bs[buf][c * 8]);
    }
  };

  const int nsteps = K >> 6;
  stage(0, 0);
  if (nsteps > 1) stage(1, 64);

  for (int t = 0; t < nsteps; ++t) {
    if (t + 1 < nsteps) asm volatile("s_waitcnt vmcnt(8)" ::: "memory");  // tile t landed, t+1 in flight
    else               asm volatile("s_waitcnt vmcnt(0)" ::: "memory");
    __syncthreads();
    if (t + 2 < nsteps) stage((t + 2) % 3, (t + 2) * 64);   // issue-ahead, covered by 2 compute phases
    const int cur = t % 3;
    const unsigned short* Ac = As[cur];
    const unsigned short* Bc = Bs[cur];
#pragma unroll
    for (int ks = 0; ks < 2; ++ks) {
      s16x8 af[4], bfr[NW];
#pragma unroll
      for (int m = 0; m < 4; ++m)
        af[m] = *(const s16x8*)&Ac[(wr * 64 + m * 16 + lr) * 64 + ks * 32 + lk * 8];
#pragma unroll
      for (int n = 0; n < NW; ++n)
        bfr[n] = *(const s16x8*)&Bc[(wc * (BN / 2) + n * 16 + lr) * 64 + ks * 32 + lk * 8];
#pragma unroll
      for (int m = 0; m < 4; ++m)
#pragma unroll
        for (int n = 0; n < NW; ++n)
          acc[m][n] = __builtin_amdgcn_mfma_f32_16x16x32_bf16(af[m], bfr[n], acc[m][n], 0, 0, 0);
    }
  }
#pragma unroll
  for (int m = 0; m < 4; ++m) {
#pragma unroll
    for (int n = 0; n < NW; ++n) {
      const int col = bx * BN + wc * (BN / 2) + n * 16 + lr;
      const float bval = bias[col];
#pragma unroll
      for (int r2 = 0; r2 < 4; ++r2) {
        const int row = by * 128 + wr * 64 + m * 16 + lk * 4 + r2;
        float vv = acc[m][n][r2] + bval;
        const size_t idx = (size_t)row * N + col;
        if (EPI == 0) {
          ((unsigned short*)Cout)[idx] = f2bf(vv);
        } else if (EPI == 1) {
          const float t2 = vv * (1.5957691216f + 0.0713548163f * vv * vv);
          ((unsigned short*)Cout)[idx] = f2bf(vv / (1.0f + __expf(-t2)));
        } else {
          ((float*)Cout)[idx] = vv + resid[idx];
        }
      }
    }
  }
}

// ---------------- flash attention v2: swapped QK^T, swizzled LDS, softmax1 ----------------
__global__ __launch_bounds__(256, 4)
void attn2(const unsigned short* __restrict__ qkv, const void* __restrict__ maskp,
           const int* __restrict__ flag, unsigned short* __restrict__ o_ws) {
  __shared__ unsigned short Qs[64 * 64];
  __shared__ unsigned short Ks[64 * 64];
  __shared__ unsigned short Vts[64 * 64];
  __shared__ unsigned short Ps[4][16 * 64];

  const int tid = threadIdx.x;
  const int orig = blockIdx.x;
  const int swzb = (orig & 7) * 128 + (orig >> 3);
  const int bh = swzb >> 4, qt = swzb & 15;
  const int b = bh >> 4, h = bh & 15;
  const int q0 = qt * 64;
  const int w = tid >> 6, l = tid & 63;
  const int lr = l & 15, lk = l >> 4;
  const size_t rowbase = (size_t)b * 1024;
  const int qoff = h * 64, koff = 1024 + h * 64, voff = 2048 + h * 64;

#pragma unroll
  for (int it = 0; it < 2; ++it) {
    const int c = it * 256 + tid;
    const int r = c >> 3, j0 = c & 7;
    const int jsrc = j0 ^ (r & 7);
    gll16(qkv + (rowbase + q0 + r) * 3072 + qoff + jsrc * 8, Qs + c * 8);
  }
  const int mask_is_byte = *flag;
  const int qrow_g = q0 + w * 16 + lr;
  const unsigned char* mrow_b = (const unsigned char*)maskp + ((size_t)b * 1024 + qrow_g) * 1024;
  const int* mrow_i = (const int*)maskp + ((size_t)b * 1024 + qrow_g) * 1024;

  const int np = tid & 31, dg = tid >> 5;

  float m_r = 0.f, l_r = 1.f;
  f32x4 acc_o[4] = {};

  for (int nt = 0; nt < 16; ++nt) {
    const int n0 = nt * 64;
    const unsigned short* vsrc = qkv + (rowbase + n0 + 2 * np) * 3072 + voff + dg * 8;
    u32x4 va = *(const u32x4*)vsrc;
    u32x4 vb = *(const u32x4*)(vsrc + 3072);
    unsigned int mb[4];
    if (mask_is_byte) {
#pragma unroll
      for (int n = 0; n < 4; ++n)
        mb[n] = *(const unsigned int*)(mrow_b + n0 + n * 16 + lk * 4);
    } else {
#pragma unroll
      for (int n = 0; n < 4; ++n) {
        u32x4 t4 = *(const u32x4*)(mrow_i + n0 + n * 16 + lk * 4);
        mb[n] = (t4.x ? 1u : 0u) | (t4.y ? 0x100u : 0u) |
                (t4.z ? 0x10000u : 0u) | (t4.w ? 0x1000000u : 0u);
      }
    }
    __syncthreads();
#pragma unroll
    for (int it = 0; it < 2; ++it) {
      const int c = it * 256 + tid;
      const int r = c >> 3, j0 = c & 7;
      const int jsrc = j0 ^ (r & 7);
      gll16(qkv + (rowbase + n0 + r) * 3072 + koff + jsrc * 8, Ks + c * 8);
    }
    {
      const unsigned short* ea = (const unsigned short*)&va;
      const unsigned short* eb = (const unsigned short*)&vb;
#pragma unroll
      for (int j = 0; j < 8; ++j) {
        const int d = dg * 8 + j;
        const unsigned int pv = (unsigned int)ea[j] | ((unsigned int)eb[j] << 16);
        const int byte = (d * 128 + np * 4) ^ ((d & 7) << 4);
        *(unsigned int*)((char*)Vts + byte) = pv;
      }
    }
    asm volatile("s_waitcnt vmcnt(0)" ::: "memory");
    __syncthreads();

    f32x4 s_acc[4] = {};
#pragma unroll
    for (int ks = 0; ks < 2; ++ks) {
      const int cb = ks * 64 + lk * 16;
      const s16x8 qf = *(const s16x8*)((char*)Qs + (((w * 16 + lr) * 128 + cb) ^ ((lr & 7) << 4)));
#pragma unroll
      for (int n = 0; n < 4; ++n) {
        const s16x8 kf = *(const s16x8*)((char*)Ks + (((n * 16 + lr) * 128 + cb) ^ ((lr & 7) << 4)));
        s_acc[n] = __builtin_amdgcn_mfma_f32_16x16x32_bf16(kf, qf, s_acc[n], 0, 0, 0);
      }
    }
    float pmax = -3.0e38f;
#pragma unroll
    for (int n = 0; n < 4; ++n)
#pragma unroll
      for (int r2 = 0; r2 < 4; ++r2) {
        float s = s_acc[n][r2] * 0.125f;
        if ((mb[n] >> (8 * r2)) & 0xff) s = -3.0e38f;
        s_acc[n][r2] = s;
        pmax = fmaxf(pmax, s);
      }
    pmax = fmaxf(pmax, __shfl_xor(pmax, 16, 64));
    pmax = fmaxf(pmax, __shfl_xor(pmax, 32, 64));
    const float mnew = fmaxf(m_r, pmax);
    const float resc = __expf(m_r - mnew);
    m_r = mnew;
    float psum = 0.f;
    unsigned int pk[4][2];
#pragma unroll
    for (int n = 0; n < 4; ++n)
#pragma unroll
      for (int h2 = 0; h2 < 2; ++h2) {
        const float p0 = __expf(s_acc[n][2 * h2]     - mnew);
        const float p1 = __expf(s_acc[n][2 * h2 + 1] - mnew);
        psum += p0 + p1;
        pk[n][h2] = (unsigned int)f2bf(p0) | ((unsigned int)f2bf(p1) << 16);
      }
    psum += __shfl_xor(psum, 16, 64);
    psum += __shfl_xor(psum, 32, 64);
    l_r = l_r * resc + psum;
    char* psw = (char*)&Ps[w][0];
#pragma unroll
    for (int n = 0; n < 4; ++n)
#pragma unroll
      for (int h2 = 0; h2 < 2; ++h2) {
        const int byte = (lr * 128 + n * 32 + lk * 8 + h2 * 4) ^ ((lr & 7) << 4);
        *(unsigned int*)(psw + byte) = pk[n][h2];
      }
    float rs4[4];
#pragma unroll
    for (int r2 = 0; r2 < 4; ++r2)
      rs4[r2] = __shfl(resc, (l & 48) | (lk * 4 + r2), 64);
#pragma unroll
    for (int dn = 0; dn < 4; ++dn)
#pragma unroll
      for (int r2 = 0; r2 < 4; ++r2) acc_o[dn][r2] *= rs4[r2];
#pragma unroll
    for (int ks = 0; ks < 2; ++ks) {
      const int cb = ks * 64 + lk * 16;
      const s16x8 ap = *(const s16x8*)(psw + ((lr * 128 + cb) ^ ((lr & 7) << 4)));
#pragma unroll
      for (int dn = 0; dn < 4; ++dn) {
        const s16x8 bv = *(const s16x8*)((char*)Vts + (((dn * 16 + lr) * 128 + cb) ^ ((lr & 7) << 4)));
        acc_o[dn] = __builtin_amdgcn_mfma_f32_16x16x32_bf16(ap, bv, acc_o[dn], 0, 0, 0);
      }
    }
  }
  const float linv = 1.0f / l_r;
  float li4[4];
#pragma unroll
  for (int r2 = 0; r2 < 4; ++r2)
    li4[r2] = __shfl(linv, (l & 48) | (lk * 4 + r2), 64);
#pragma unroll
  for (int dn = 0; dn < 4; ++dn)
#pragma unroll
    for (int r2 = 0; r2 < 4; ++r2) {
      const int qrow = q0 + w * 16 + lk * 4 + r2;
      const int dcol = h * 64 + dn * 16 + lr;
      o_ws[(rowbase + qrow) * 1024 + dcol] = f2bf(acc_o[dn][r2] * li4[r2]);
    }
}

// ---------------- launch ----------------
extern "C" void kernel_launch(void* const* d_in, const int* in_sizes, int n_in,
                              void* d_out, int out_size, void* d_ws, size_t ws_size,
                              hipStream_t stream) {
  const float* x      = (const float*)d_in[0];
  const void*  maskp  = d_in[1];
  const float* ln1_g  = (const float*)d_in[2];
  const float* ln1_b  = (const float*)d_in[3];
  const float* qkv_w  = (const float*)d_in[4];
  const float* qkv_b  = (const float*)d_in[5];
  const float* proj_w = (const float*)d_in[6];
  const float* proj_b = (const float*)d_in[7];
  const float* ln2_g  = (const float*)d_in[8];
  const float* ln2_b  = (const float*)d_in[9];
  const float* fc1_w  = (const float*)d_in[10];
  const float* fc1_b  = (const float*)d_in[11];
  const float* fc2_w  = (const float*)d_in[12];
  const float* fc2_b  = (const float*)d_in[13];
  float* out = (float*)d_out;

  char* ws = (char*)d_ws;
  int* flag            = (int*)ws;                                   // 256 B
  unsigned short* bufA = (unsigned short*)(ws + 256);                // 33.6 MB
  unsigned short* bufH = (unsigned short*)(ws + 256 + 33554432);     // 8.4 MB
  unsigned short* bufO = (unsigned short*)(ws + 256 + 33554432 + 8388608);          // 8.4 MB
  float* bufX1         = (float*)(ws + 256 + 33554432 + 2 * 8388608);               // 16.8 MB
  char* wbase          = ws + 256 + 33554432 + 2 * 8388608 + 16777216;

  const bool bigws = ws_size >= (size_t)92274944;
  if (bigws) {
    unsigned short* W0 = (unsigned short*)wbase;                 // qkv  6.3 MB
    unsigned short* W1 = (unsigned short*)(wbase + 6291456);     // proj 2.1 MB
    unsigned short* W2 = (unsigned short*)(wbase + 8388608);     // fc1  8.4 MB
    unsigned short* W3 = (unsigned short*)(wbase + 16777216);    // fc2  8.4 MB
    convert_weights<<<4096, 256, 0, stream>>>(qkv_w, proj_w, fc1_w, fc2_w, W0, W1, W2, W3,
                                              (const unsigned char*)maskp, flag);
    ln_bf16<<<4096, 256, 0, stream>>>(x, ln1_g, ln1_b, bufH);
    gemm256<0><<<192, 512, 0, stream>>>(bufH, W0, qkv_b, bufA, 4096, 3072, 1024, 12);
    attn2<<<1024, 256, 0, stream>>>(bufA, maskp, flag, bufO);
    gemm_bt<2, 4><<<256, 256, 0, stream>>>(bufO, W1, proj_b, x, bufX1, 4096, 1024, 1024, 8);
    ln_bf16<<<4096, 256, 0, stream>>>(bufX1, ln2_g, ln2_b, bufH);
    gemm256<1><<<256, 512, 0, stream>>>(bufH, W2, fc1_b, bufA, 4096, 4096, 1024, 16);
    gemm_bt<2, 4><<<256, 256, 0, stream>>>(bufA, W3, fc2_b, bufX1, out, 4096, 1024, 4096, 8);
  } else {
    unsigned short* bufW = (unsigned short*)wbase;               // shared 8.4 MB
    mask_detect<<<1, 256, 0, stream>>>((const unsigned char*)maskp, flag);
    ln_bf16<<<4096, 256, 0, stream>>>(x, ln1_g, ln1_b, bufH);
    f32_to_bf16<<<2048, 256, 0, stream>>>(qkv_w, bufW, 3072 * 1024);
    gemm256<0><<<192, 512, 0, stream>>>(bufH, bufW, qkv_b, bufA, 4096, 3072, 1024, 12);
    attn2<<<1024, 256, 0, stream>>>(bufA, maskp, flag, bufO);
    f32_to_bf16<<<2048, 256, 0, stream>>>(proj_w, bufW, 1024 * 1024);
    gemm_bt<2, 4><<<256, 256, 0, stream>>>(bufO, bufW, proj_b, x, bufX1, 4096, 1024, 1024, 8);
    ln_bf16<<<4096, 256, 0, stream>>>(bufX1, ln2_g, ln2_b, bufH);
    f32_to_bf16<<<2048, 256, 0, stream>>>(fc1_w, bufW, 4096 * 1024);
    gemm256<1><<<256, 512, 0, stream>>>(bufH, bufW, fc1_b, bufA, 4096, 4096, 1024, 16);
    f32_to_bf16<<<2048, 256, 0, stream>>>(fc2_w, bufW, 1024 * 4096);
    gemm_bt<2, 4><<<256, 256, 0, stream>>>(bufA, bufW, fc2_b, bufX1, out, 4096, 1024, 4096, 8);
  }
}